// Round 1
// baseline (271.758 us; speedup 1.0000x reference)
//
#include <hip/hip_runtime.h>

typedef unsigned short bfu;
typedef __attribute__((ext_vector_type(8))) short short8;
typedef __attribute__((ext_vector_type(4))) float f32x4;

__device__ __forceinline__ float bf2f(bfu u){
  union { unsigned int i; float f; } v; v.i = ((unsigned int)u) << 16; return v.f;
}
__device__ __forceinline__ bfu f2bf(float f){
  union { float f; unsigned int i; } v; v.f = f;
  unsigned int r = (v.i + 0x7FFFu + ((v.i >> 16) & 1u)) >> 16;
  return (bfu)r;
}
__device__ __forceinline__ float softplusf(float x){
  return (x > 20.f) ? x : log1pf(__expf(x));
}

// ---------------- conversion kernels ----------------
__global__ __launch_bounds__(256) void cvt4_kernel(const float* __restrict__ in, bfu* __restrict__ out, int n4){
  int g = blockIdx.x * 256 + threadIdx.x;
  if (g < n4){
    float4 v = ((const float4*)in)[g];
    ushort4 o;
    o.x = f2bf(v.x); o.y = f2bf(v.y); o.z = f2bf(v.z); o.w = f2bf(v.w);
    ((ushort4*)out)[g] = o;
  }
}

// in[R][C] (f32) -> out[C][R] (bf16)
__global__ __launch_bounds__(256) void cvtT_kernel(const float* __restrict__ in, bfu* __restrict__ out, int R, int C){
  int g = blockIdx.x * 256 + threadIdx.x;
  if (g < R * C){
    int r = g % R, c = g / R;
    out[g] = f2bf(in[(size_t)r * C + c]);
  }
}

// ---------------- MFMA GEMM: C = A(MxK) * Bt(NxK)^T ----------------
// EPI 0: silu epilogue, split write to out0 (cols<768) / out1 (cols>=768), bf16
// EPI 1: plain f32 write to out0
template<int EPI>
__global__ __launch_bounds__(256)
void gemm_bt(const bfu* __restrict__ Amat, const bfu* __restrict__ Bt,
             void* __restrict__ out0, void* __restrict__ out1,
             int M, int N, int K)
{
  __shared__ bfu As[128 * 32];
  __shared__ bfu Bs[128 * 32];
  const int tid  = threadIdx.x;
  const int lane = tid & 63;
  const int w    = tid >> 6;
  const int wr   = w >> 1, wc = w & 1;
  const int bn = blockIdx.x, bm = blockIdx.y;

  // staging: 256 threads, each loads 16B from two row-halves of A and B tiles
  const int r0 = tid >> 2;            // 0..63
  const int r1 = r0 + 64;             // 64..127
  const int co = (tid & 3) * 8;       // 0,8,16,24 (bf16 elems)
  const bfu* gA0 = Amat + ((size_t)(bm * 128 + r0)) * K + co;
  const bfu* gA1 = Amat + ((size_t)(bm * 128 + r1)) * K + co;
  const bfu* gB0 = Bt   + ((size_t)(bn * 128 + r0)) * K + co;
  const bfu* gB1 = Bt   + ((size_t)(bn * 128 + r1)) * K + co;
  float4* lA0 = (float4*)(As + r0 * 32 + co);
  float4* lA1 = (float4*)(As + r1 * 32 + co);
  float4* lB0 = (float4*)(Bs + r0 * 32 + co);
  float4* lB1 = (float4*)(Bs + r1 * 32 + co);

  f32x4 acc[4][4];
  #pragma unroll
  for (int i = 0; i < 4; i++)
    #pragma unroll
    for (int j = 0; j < 4; j++)
      #pragma unroll
      for (int r = 0; r < 4; r++) acc[i][j][r] = 0.f;

  for (int k0 = 0; k0 < K; k0 += 32){
    float4 a0 = *(const float4*)(gA0 + k0);
    float4 a1 = *(const float4*)(gA1 + k0);
    float4 b0 = *(const float4*)(gB0 + k0);
    float4 b1 = *(const float4*)(gB1 + k0);
    *lA0 = a0; *lA1 = a1; *lB0 = b0; *lB1 = b1;
    __syncthreads();

    short8 a[4], b[4];
    #pragma unroll
    for (int m = 0; m < 4; m++)
      a[m] = *(const short8*)&As[(wr * 64 + m * 16 + (lane & 15)) * 32 + (lane >> 4) * 8];
    #pragma unroll
    for (int n = 0; n < 4; n++)
      b[n] = *(const short8*)&Bs[(wc * 64 + n * 16 + (lane & 15)) * 32 + (lane >> 4) * 8];
    #pragma unroll
    for (int m = 0; m < 4; m++)
      #pragma unroll
      for (int n = 0; n < 4; n++)
        acc[m][n] = __builtin_amdgcn_mfma_f32_16x16x32_bf16(a[m], b[n], acc[m][n], 0, 0, 0);
    __syncthreads();
  }

  #pragma unroll
  for (int m = 0; m < 4; m++){
    #pragma unroll
    for (int n = 0; n < 4; n++){
      const int row0 = bm * 128 + wr * 64 + m * 16 + (lane >> 4) * 4;
      const int col  = bn * 128 + wc * 64 + n * 16 + (lane & 15);
      #pragma unroll
      for (int r = 0; r < 4; r++){
        float v = acc[m][n][r];
        int row = row0 + r;
        if (EPI == 0){
          float s = v / (1.f + __expf(-v));   // silu
          if (col < 768) ((bfu*)out0)[(size_t)row * 768 + col]         = f2bf(s);
          else           ((bfu*)out1)[(size_t)row * 768 + (col - 768)] = f2bf(s);
        } else {
          ((float*)out0)[(size_t)row * N + col] = v;
        }
      }
    }
  }
}

// ---------------- u = x_ssm @ W_x   (16384 x 768) @ (768 x 8) ----------------
__global__ __launch_bounds__(256) void gemm_u(const bfu* __restrict__ xssm, const float* __restrict__ Wx,
                                              float* __restrict__ u){
  int wid = threadIdx.x >> 6, lane = threadIdx.x & 63;
  int row = blockIdx.x * 4 + wid;
  const bfu* xr = xssm + (size_t)row * 768;
  float acc[8];
  #pragma unroll
  for (int n = 0; n < 8; n++) acc[n] = 0.f;
  #pragma unroll
  for (int i = 0; i < 3; i++){
    int kb = i * 256 + lane * 4;
    ushort4 xq = *(const ushort4*)(xr + kb);
    float xv[4] = { bf2f(xq.x), bf2f(xq.y), bf2f(xq.z), bf2f(xq.w) };
    #pragma unroll
    for (int j = 0; j < 4; j++){
      const float* wp = Wx + (size_t)(kb + j) * 8;
      float4 w0 = *(const float4*)wp;
      float4 w1 = *(const float4*)(wp + 4);
      acc[0] += xv[j] * w0.x; acc[1] += xv[j] * w0.y; acc[2] += xv[j] * w0.z; acc[3] += xv[j] * w0.w;
      acc[4] += xv[j] * w1.x; acc[5] += xv[j] * w1.y; acc[6] += xv[j] * w1.z; acc[7] += xv[j] * w1.w;
    }
  }
  #pragma unroll
  for (int n = 0; n < 8; n++){
    #pragma unroll
    for (int off = 32; off >= 1; off >>= 1) acc[n] += __shfl_xor(acc[n], off, 64);
  }
  if (lane == 0){
    #pragma unroll
    for (int n = 0; n < 8; n++) u[(size_t)row * 8 + n] = acc[n];
  }
}

// ---------------- delta = softplus(u @ W_dt + b_dt)  -> bf16 ----------------
__global__ __launch_bounds__(192) void delta_kernel(const float* __restrict__ u, const float* __restrict__ Wdt,
                                                    const float* __restrict__ bdt, bfu* __restrict__ delta){
  int r = blockIdx.x;
  int d0 = threadIdx.x * 4;
  const float* ur = u + (size_t)r * 8;
  float4 acc = *(const float4*)(bdt + d0);
  #pragma unroll
  for (int n = 0; n < 8; n++){
    float4 wv = *(const float4*)(Wdt + (size_t)n * 768 + d0);
    float un = ur[n];
    acc.x += un * wv.x; acc.y += un * wv.y; acc.z += un * wv.z; acc.w += un * wv.w;
  }
  ushort4 o;
  o.x = f2bf(softplusf(acc.x)); o.y = f2bf(softplusf(acc.y));
  o.z = f2bf(softplusf(acc.z)); o.w = f2bf(softplusf(acc.w));
  *(ushort4*)(delta + (size_t)r * 768 + d0) = o;
}

// ---------------- scan phase 1: per-chunk local scan ----------------
// grid: b(8) x c(64) x dblk(3), block 256 -> d = dblk*256+tid
__global__ __launch_bounds__(256) void scan_phase1(const bfu* __restrict__ xssm, const bfu* __restrict__ delta,
    const float* __restrict__ A_log, float* __restrict__ Pws, float* __restrict__ Hws){
  int tid = threadIdx.x;
  int bid = blockIdx.x;
  int b = bid / 192; int rem = bid % 192;
  int c = rem / 3;   int dblk = rem % 3;
  int d = dblk * 256 + tid;
  float Al2[8], P[8], H[8];
  #pragma unroll
  for (int n = 0; n < 8; n++){
    Al2[n] = -expf(A_log[(size_t)d * 8 + n]) * 1.4426950408889634f;
    P[n] = 1.f; H[n] = 0.f;
  }
  size_t base = ((size_t)b * 2048 + (size_t)c * 32) * 768 + d;
  #pragma unroll 4
  for (int i = 0; i < 32; i++){
    size_t idx = base + (size_t)i * 768;
    float xt = bf2f(xssm[idx]);
    float dt = bf2f(delta[idx]);
    float dx = dt * xt;
    #pragma unroll
    for (int n = 0; n < 8; n++){
      float e = exp2f(dt * Al2[n]);
      H[n] = e * H[n] + dx;
      P[n] *= e;
    }
  }
  size_t o = (((size_t)b * 768 + d) * 64 + c) * 8;
  #pragma unroll
  for (int n = 0; n < 8; n++){ Pws[o + n] = P[n]; Hws[o + n] = H[n]; }
}

// ---------------- scan phase 2: combine chunks ----------------
__global__ __launch_bounds__(256) void scan_phase2(const float* __restrict__ Pws, const float* __restrict__ Hws,
                                                   float* __restrict__ Hin){
  int g = blockIdx.x * 256 + threadIdx.x;   // 49152 = 8*768*8
  int n = g & 7; size_t bd = (size_t)(g >> 3);
  size_t base = bd * 512 + n;
  float hin = 0.f;
  #pragma unroll 8
  for (int c = 0; c < 64; c++){
    size_t idx = base + (size_t)c * 8;
    float p = Pws[idx], hh = Hws[idx];
    Hin[idx] = hin;
    hin = p * hin + hh;
  }
}

// ---------------- scan phase 3: re-run chunk with h_in, fuse gate ----------------
__global__ __launch_bounds__(256) void scan_phase3(const bfu* __restrict__ xssm, const bfu* __restrict__ delta,
    const bfu* __restrict__ siluz, const float* __restrict__ A_log, const float* __restrict__ Dp,
    const float* __restrict__ Hin, bfu* __restrict__ yz){
  int tid = threadIdx.x;
  int bid = blockIdx.x;
  int b = bid / 192; int rem = bid % 192;
  int c = rem / 3;   int dblk = rem % 3;
  int d = dblk * 256 + tid;
  float Al2[8], H[8];
  size_t o = (((size_t)b * 768 + d) * 64 + c) * 8;
  #pragma unroll
  for (int n = 0; n < 8; n++){
    Al2[n] = -expf(A_log[(size_t)d * 8 + n]) * 1.4426950408889634f;
    H[n] = Hin[o + n];
  }
  float Dd = Dp[d];
  size_t base = ((size_t)b * 2048 + (size_t)c * 32) * 768 + d;
  #pragma unroll 4
  for (int i = 0; i < 32; i++){
    size_t idx = base + (size_t)i * 768;
    float xt = bf2f(xssm[idx]);
    float dt = bf2f(delta[idx]);
    float dx = dt * xt;
    float y = Dd * xt;
    #pragma unroll
    for (int n = 0; n < 8; n++){
      float e = exp2f(dt * Al2[n]);
      H[n] = e * H[n] + dx;
      y += H[n];
    }
    float sz = bf2f(siluz[idx]);
    yz[idx] = f2bf(y * sz);
  }
}

extern "C" void kernel_launch(void* const* d_in, const int* in_sizes, int n_in,
                              void* d_out, int out_size, void* d_ws, size_t ws_size,
                              hipStream_t stream){
  const float* x     = (const float*)d_in[0];
  const float* W_in  = (const float*)d_in[1];
  const float* A_log = (const float*)d_in[2];
  const float* D_par = (const float*)d_in[3];
  const float* W_x   = (const float*)d_in[4];
  const float* W_dt  = (const float*)d_in[5];
  const float* b_dt  = (const float*)d_in[6];
  const float* W_out = (const float*)d_in[7];
  float* out = (float*)d_out;
  (void)in_sizes; (void)n_in; (void)out_size; (void)ws_size;

  char* base = (char*)d_ws;
  size_t off = 0;
  auto alloc = [&](size_t bytes)->char*{
    char* p = base + off; off += (bytes + 255) & ~(size_t)255; return p;
  };
  bfu*   x_bf  = (bfu*)  alloc((size_t)16384 * 512 * 2);
  bfu*   WinT  = (bfu*)  alloc((size_t)1536 * 512 * 2);
  bfu*   WoutT = (bfu*)  alloc((size_t)512 * 768 * 2);
  bfu*   xssm  = (bfu*)  alloc((size_t)16384 * 768 * 2);
  bfu*   siluz = (bfu*)  alloc((size_t)16384 * 768 * 2);
  bfu*   delta = (bfu*)  alloc((size_t)16384 * 768 * 2);
  float* u     = (float*)alloc((size_t)16384 * 8 * 4);
  float* Pws   = (float*)alloc((size_t)8 * 768 * 64 * 8 * 4);
  float* Hws   = (float*)alloc((size_t)8 * 768 * 64 * 8 * 4);
  float* Hin   = (float*)alloc((size_t)8 * 768 * 64 * 8 * 4);
  bfu*   yz    = (bfu*)  alloc((size_t)16384 * 768 * 2);

  // 1) convert x to bf16 (8388608 elems = 2097152 x4)
  cvt4_kernel<<<8192, 256, 0, stream>>>(x, x_bf, 2097152);
  // 2) transpose+convert weights: W_in (512x1536)->WinT(1536x512), W_out(768x512)->WoutT(512x768)
  cvtT_kernel<<<3072, 256, 0, stream>>>(W_in, WinT, 512, 1536);
  cvtT_kernel<<<1536, 256, 0, stream>>>(W_out, WoutT, 768, 512);
  // 3) GEMM1: xz = x @ W_in, fused silu + split -> xssm, siluz (bf16)
  gemm_bt<0><<<dim3(12, 128), 256, 0, stream>>>(x_bf, WinT, xssm, siluz, 16384, 1536, 512);
  // 4) u = xssm @ W_x (f32)
  gemm_u<<<4096, 256, 0, stream>>>(xssm, W_x, u);
  // 5) delta = softplus(u @ W_dt + b_dt) (bf16)
  delta_kernel<<<16384, 192, 0, stream>>>(u, W_dt, b_dt, delta);
  // 6-8) chunked scan
  scan_phase1<<<1536, 256, 0, stream>>>(xssm, delta, A_log, Pws, Hws);
  scan_phase2<<<192, 256, 0, stream>>>(Pws, Hws, Hin);
  scan_phase3<<<1536, 256, 0, stream>>>(xssm, delta, siluz, A_log, D_par, Hin, yz);
  // 9) out = yz @ W_out (f32 out)
  gemm_bt<1><<<dim3(4, 128), 256, 0, stream>>>(yz, WoutT, out, nullptr, 16384, 512, 768);
}

// Round 2
// 231.862 us; speedup vs baseline: 1.1721x; 1.1721x over previous
//
#include <hip/hip_runtime.h>

typedef unsigned short bfu;
typedef __attribute__((ext_vector_type(8))) short short8;
typedef __attribute__((ext_vector_type(4))) float f32x4;

__device__ __forceinline__ float bf2f(bfu u){
  union { unsigned int i; float f; } v; v.i = ((unsigned int)u) << 16; return v.f;
}
__device__ __forceinline__ bfu f2bf(float f){
  union { float f; unsigned int i; } v; v.f = f;
  unsigned int r = (v.i + 0x7FFFu + ((v.i >> 16) & 1u)) >> 16;
  return (bfu)r;
}
__device__ __forceinline__ float softplusf(float x){
  return (x > 20.f) ? x : log1pf(__expf(x));
}
__device__ __forceinline__ void gload16(const bfu* g, bfu* l){
  __builtin_amdgcn_global_load_lds((const __attribute__((address_space(1))) unsigned int*)g,
                                   (__attribute__((address_space(3))) unsigned int*)l, 16, 0, 0);
}

// ---------------- conversion kernels ----------------
__global__ __launch_bounds__(256) void cvt4_kernel(const float* __restrict__ in, bfu* __restrict__ out, int n4){
  int g = blockIdx.x * 256 + threadIdx.x;
  if (g < n4){
    float4 v = ((const float4*)in)[g];
    ushort4 o;
    o.x = f2bf(v.x); o.y = f2bf(v.y); o.z = f2bf(v.z); o.w = f2bf(v.w);
    ((ushort4*)out)[g] = o;
  }
}

// W_in (512x1536) -> WinT (1536x512) bf16 ; W_out (768x512) -> WoutT (512x768) bf16
__global__ __launch_bounds__(256) void cvtT2_kernel(const float* __restrict__ W_in, const float* __restrict__ W_out,
                                                    bfu* __restrict__ WinT, bfu* __restrict__ WoutT){
  int g = blockIdx.x * 256 + threadIdx.x;
  if (g < 786432){
    int r = g % 512, c = g / 512;
    WinT[g] = f2bf(W_in[(size_t)r * 1536 + c]);
  } else if (g < 786432 + 393216){
    int h = g - 786432;
    int r = h % 768, c = h / 768;
    WoutT[h] = f2bf(W_out[(size_t)r * 512 + c]);
  }
}

// ---------------- MFMA GEMM: C = A(MxK) * Bt(NxK)^T ----------------
// m97-style: 128x128 tile, BK=64, global_load_lds(16B), XOR-swizzled LDS (T2).
// EPI 0: silu epilogue, split write to out0 (cols<768) / out1 (cols>=768), bf16
// EPI 1: plain f32 write to out0 (row-stride N)
template<int EPI>
__global__ __launch_bounds__(256)
void gemm_bt(const bfu* __restrict__ Amat, const bfu* __restrict__ Bt,
             void* __restrict__ out0, void* __restrict__ out1,
             int M, int N, int K)
{
  __shared__ bfu As[128 * 64];
  __shared__ bfu Bs[128 * 64];
  const int tid  = threadIdx.x;
  const int lane = tid & 63;
  const int w    = tid >> 6;
  const int wr   = w >> 1, wc = w & 1;
  const int bn = blockIdx.x, bm = blockIdx.y;

  // staging: per issue i (4 per operand), wave w stages rows i*32 + w*8 .. +7
  // lane l covers row (l>>3), 16B slot (l&7); global col pre-swizzled: slot ^ (row&7)
  const int srow = w * 8 + (lane >> 3);
  const int scol = ((lane & 7) ^ (lane >> 3)) * 8;
  const bfu* gA = Amat + ((size_t)(bm * 128 + srow)) * K + scol;
  const bfu* gB = Bt   + ((size_t)(bn * 128 + srow)) * K + scol;
  bfu* lA = As + (w * 8) * 64;
  bfu* lB = Bs + (w * 8) * 64;

  f32x4 acc[4][4];
  #pragma unroll
  for (int i = 0; i < 4; i++)
    #pragma unroll
    for (int j = 0; j < 4; j++)
      #pragma unroll
      for (int r = 0; r < 4; r++) acc[i][j][r] = 0.f;

  for (int k0 = 0; k0 < K; k0 += 64){
    #pragma unroll
    for (int i = 0; i < 4; i++){
      gload16(gA + (size_t)(i * 32) * K + k0, lA + i * 32 * 64);
      gload16(gB + (size_t)(i * 32) * K + k0, lB + i * 32 * 64);
    }
    __syncthreads();   // drains vmcnt -> tiles visible

    #pragma unroll
    for (int kk = 0; kk < 2; kk++){
      short8 a[4], b[4];
      // fragment row r has r&7 == lane&7; swizzled slot = (kk*4 + (lane>>4)) ^ (lane&7)
      const int sA = ((kk * 4 + (lane >> 4)) ^ (lane & 7)) * 8;
      #pragma unroll
      for (int m = 0; m < 4; m++){
        int r = wr * 64 + m * 16 + (lane & 15);
        a[m] = *(const short8*)&As[r * 64 + sA];
      }
      #pragma unroll
      for (int n = 0; n < 4; n++){
        int r = wc * 64 + n * 16 + (lane & 15);
        b[n] = *(const short8*)&Bs[r * 64 + sA];
      }
      #pragma unroll
      for (int m = 0; m < 4; m++)
        #pragma unroll
        for (int n = 0; n < 4; n++)
          acc[m][n] = __builtin_amdgcn_mfma_f32_16x16x32_bf16(a[m], b[n], acc[m][n], 0, 0, 0);
    }
    __syncthreads();   // all reads done before next stage overwrites
  }

  #pragma unroll
  for (int m = 0; m < 4; m++){
    #pragma unroll
    for (int n = 0; n < 4; n++){
      const int row0 = bm * 128 + wr * 64 + m * 16 + (lane >> 4) * 4;
      const int col  = bn * 128 + wc * 64 + n * 16 + (lane & 15);
      #pragma unroll
      for (int r = 0; r < 4; r++){
        float v = acc[m][n][r];
        int row = row0 + r;
        if (EPI == 0){
          float s = v / (1.f + __expf(-v));   // silu
          if (col < 768) ((bfu*)out0)[(size_t)row * 768 + col]         = f2bf(s);
          else           ((bfu*)out1)[(size_t)row * 768 + (col - 768)] = f2bf(s);
        } else {
          ((float*)out0)[(size_t)row * N + col] = v;
        }
      }
    }
  }
}

// ---------------- fused: u = xssm @ W_x ; delta = softplus(u @ W_dt + b_dt) ----------------
// one wave per row; butterfly reduce leaves u[8] in every lane; each lane emits 12 delta cols
__global__ __launch_bounds__(256) void udelta_kernel(const bfu* __restrict__ xssm, const float* __restrict__ Wx,
                                                     const float* __restrict__ Wdt, const float* __restrict__ bdt,
                                                     bfu* __restrict__ delta){
  int wid = threadIdx.x >> 6, lane = threadIdx.x & 63;
  int row = blockIdx.x * 4 + wid;
  const bfu* xr = xssm + (size_t)row * 768;
  float acc[8];
  #pragma unroll
  for (int n = 0; n < 8; n++) acc[n] = 0.f;
  #pragma unroll
  for (int i = 0; i < 3; i++){
    int kb = i * 256 + lane * 4;
    ushort4 xq = *(const ushort4*)(xr + kb);
    float xv[4] = { bf2f(xq.x), bf2f(xq.y), bf2f(xq.z), bf2f(xq.w) };
    #pragma unroll
    for (int j = 0; j < 4; j++){
      const float* wp = Wx + (size_t)(kb + j) * 8;
      float4 w0 = *(const float4*)wp;
      float4 w1 = *(const float4*)(wp + 4);
      acc[0] += xv[j] * w0.x; acc[1] += xv[j] * w0.y; acc[2] += xv[j] * w0.z; acc[3] += xv[j] * w0.w;
      acc[4] += xv[j] * w1.x; acc[5] += xv[j] * w1.y; acc[6] += xv[j] * w1.z; acc[7] += xv[j] * w1.w;
    }
  }
  #pragma unroll
  for (int n = 0; n < 8; n++){
    #pragma unroll
    for (int off = 32; off >= 1; off >>= 1) acc[n] += __shfl_xor(acc[n], off, 64);
  }
  bfu* dr = delta + (size_t)row * 768;
  #pragma unroll
  for (int j = 0; j < 12; j++){
    int d = j * 64 + lane;
    float v = bdt[d];
    #pragma unroll
    for (int n = 0; n < 8; n++) v += acc[n] * Wdt[(size_t)n * 768 + d];
    dr[d] = f2bf(softplusf(v));
  }
}

// ---------------- scan phase 1: per-chunk local scan ----------------
// grid: b(8) x c(64) x dblk(3), block 256 -> d = dblk*256+tid
// P/H layout: [b][c][d][n] (coalesced writes)
__global__ __launch_bounds__(256) void scan_phase1(const bfu* __restrict__ xssm, const bfu* __restrict__ delta,
    const float* __restrict__ A_log, float* __restrict__ Pws, float* __restrict__ Hws){
  int tid = threadIdx.x;
  int bid = blockIdx.x;
  int b = bid / 192; int rem = bid % 192;
  int c = rem / 3;   int dblk = rem % 3;
  int d = dblk * 256 + tid;
  float Al2[8], P[8], H[8];
  #pragma unroll
  for (int n = 0; n < 8; n++){
    Al2[n] = -expf(A_log[(size_t)d * 8 + n]) * 1.4426950408889634f;
    P[n] = 1.f; H[n] = 0.f;
  }
  size_t base = ((size_t)b * 2048 + (size_t)c * 32) * 768 + d;
  #pragma unroll 4
  for (int i = 0; i < 32; i++){
    size_t idx = base + (size_t)i * 768;
    float xt = bf2f(xssm[idx]);
    float dt = bf2f(delta[idx]);
    float dx = dt * xt;
    #pragma unroll
    for (int n = 0; n < 8; n++){
      float e = exp2f(dt * Al2[n]);
      H[n] = e * H[n] + dx;
      P[n] *= e;
    }
  }
  size_t o = (((size_t)b * 64 + c) * 768 + d) * 8;
  #pragma unroll
  for (int n = 0; n < 8; n++){ Pws[o + n] = P[n]; Hws[o + n] = H[n]; }
}

// ---------------- scan phase 2: combine chunks ----------------
__global__ __launch_bounds__(256) void scan_phase2(const float* __restrict__ Pws, const float* __restrict__ Hws,
                                                   float* __restrict__ Hin){
  int g = blockIdx.x * 256 + threadIdx.x;   // 49152 = 8*768*8
  int within = g % 6144;                    // d*8+n
  int b = g / 6144;
  size_t base = (size_t)b * 64 * 6144 + within;
  float hin = 0.f;
  #pragma unroll 8
  for (int c = 0; c < 64; c++){
    size_t idx = base + (size_t)c * 6144;
    float p = Pws[idx], hh = Hws[idx];
    Hin[idx] = hin;
    hin = p * hin + hh;
  }
}

// ---------------- scan phase 3: re-run chunk with h_in, fuse gate ----------------
__global__ __launch_bounds__(256) void scan_phase3(const bfu* __restrict__ xssm, const bfu* __restrict__ delta,
    const bfu* __restrict__ siluz, const float* __restrict__ A_log, const float* __restrict__ Dp,
    const float* __restrict__ Hin, bfu* __restrict__ yz){
  int tid = threadIdx.x;
  int bid = blockIdx.x;
  int b = bid / 192; int rem = bid % 192;
  int c = rem / 3;   int dblk = rem % 3;
  int d = dblk * 256 + tid;
  float Al2[8], H[8];
  size_t o = (((size_t)b * 64 + c) * 768 + d) * 8;
  #pragma unroll
  for (int n = 0; n < 8; n++){
    Al2[n] = -expf(A_log[(size_t)d * 8 + n]) * 1.4426950408889634f;
    H[n] = Hin[o + n];
  }
  float Dd = Dp[d];
  size_t base = ((size_t)b * 2048 + (size_t)c * 32) * 768 + d;
  #pragma unroll 4
  for (int i = 0; i < 32; i++){
    size_t idx = base + (size_t)i * 768;
    float xt = bf2f(xssm[idx]);
    float dt = bf2f(delta[idx]);
    float dx = dt * xt;
    float y = Dd * xt;
    #pragma unroll
    for (int n = 0; n < 8; n++){
      float e = exp2f(dt * Al2[n]);
      H[n] = e * H[n] + dx;
      y += H[n];
    }
    float sz = bf2f(siluz[idx]);
    yz[idx] = f2bf(y * sz);
  }
}

extern "C" void kernel_launch(void* const* d_in, const int* in_sizes, int n_in,
                              void* d_out, int out_size, void* d_ws, size_t ws_size,
                              hipStream_t stream){
  const float* x     = (const float*)d_in[0];
  const float* W_in  = (const float*)d_in[1];
  const float* A_log = (const float*)d_in[2];
  const float* D_par = (const float*)d_in[3];
  const float* W_x   = (const float*)d_in[4];
  const float* W_dt  = (const float*)d_in[5];
  const float* b_dt  = (const float*)d_in[6];
  const float* W_out = (const float*)d_in[7];
  float* out = (float*)d_out;
  (void)in_sizes; (void)n_in; (void)out_size; (void)ws_size;

  char* base = (char*)d_ws;
  size_t off = 0;
  auto alloc = [&](size_t bytes)->char*{
    char* p = base + off; off += (bytes + 255) & ~(size_t)255; return p;
  };
  bfu*   x_bf  = (bfu*)  alloc((size_t)16384 * 512 * 2);
  bfu*   WinT  = (bfu*)  alloc((size_t)1536 * 512 * 2);
  bfu*   WoutT = (bfu*)  alloc((size_t)512 * 768 * 2);
  bfu*   xssm  = (bfu*)  alloc((size_t)16384 * 768 * 2);
  bfu*   siluz = (bfu*)  alloc((size_t)16384 * 768 * 2);
  bfu*   delta = (bfu*)  alloc((size_t)16384 * 768 * 2);
  float* Pws   = (float*)alloc((size_t)8 * 64 * 768 * 8 * 4);
  float* Hws   = (float*)alloc((size_t)8 * 64 * 768 * 8 * 4);
  float* Hin   = (float*)alloc((size_t)8 * 64 * 768 * 8 * 4);
  bfu*   yz    = (bfu*)  alloc((size_t)16384 * 768 * 2);

  // 1) convert x to bf16
  cvt4_kernel<<<8192, 256, 0, stream>>>(x, x_bf, 2097152);
  // 2) transpose+convert both weight matrices
  cvtT2_kernel<<<4608, 256, 0, stream>>>(W_in, W_out, WinT, WoutT);
  // 3) GEMM1: xz = x @ W_in, fused silu + split -> xssm, siluz (bf16)
  gemm_bt<0><<<dim3(12, 128), 256, 0, stream>>>(x_bf, WinT, xssm, siluz, 16384, 1536, 512);
  // 4) u + delta fused
  udelta_kernel<<<4096, 256, 0, stream>>>(xssm, W_x, W_dt, b_dt, delta);
  // 5-7) chunked scan
  scan_phase1<<<1536, 256, 0, stream>>>(xssm, delta, A_log, Pws, Hws);
  scan_phase2<<<192, 256, 0, stream>>>(Pws, Hws, Hin);
  scan_phase3<<<1536, 256, 0, stream>>>(xssm, delta, siluz, A_log, D_par, Hin, yz);
  // 8) out = yz @ W_out (f32 out)
  gemm_bt<1><<<dim3(4, 128), 256, 0, stream>>>(yz, WoutT, out, nullptr, 16384, 512, 768);
}

// Round 3
// 201.443 us; speedup vs baseline: 1.3491x; 1.1510x over previous
//
#include <hip/hip_runtime.h>

typedef unsigned short bfu;
typedef __attribute__((ext_vector_type(8))) short short8;
typedef __attribute__((ext_vector_type(4))) float f32x4;

__device__ __forceinline__ float bf2f(bfu u){
  union { unsigned int i; float f; } v; v.i = ((unsigned int)u) << 16; return v.f;
}
__device__ __forceinline__ bfu f2bf(float f){
  union { float f; unsigned int i; } v; v.f = f;
  unsigned int r = (v.i + 0x7FFFu + ((v.i >> 16) & 1u)) >> 16;
  return (bfu)r;
}
// fast softplus: max(x,0) + log(1+exp(-|x|)); ~6 instrs, bf16-accurate
__device__ __forceinline__ float softplusf(float x){
  return fmaxf(x, 0.f) + __logf(1.f + __expf(-fabsf(x)));
}
__device__ __forceinline__ void gload16(const bfu* g, bfu* l){
  __builtin_amdgcn_global_load_lds((const __attribute__((address_space(1))) unsigned int*)g,
                                   (__attribute__((address_space(3))) unsigned int*)l, 16, 0, 0);
}

// ---------------- conversion kernels ----------------
__global__ __launch_bounds__(256) void cvt4_kernel(const float* __restrict__ in, bfu* __restrict__ out, int n4){
  int g = blockIdx.x * 256 + threadIdx.x;
  if (g < n4){
    float4 v = ((const float4*)in)[g];
    ushort4 o;
    o.x = f2bf(v.x); o.y = f2bf(v.y); o.z = f2bf(v.z); o.w = f2bf(v.w);
    ((ushort4*)out)[g] = o;
  }
}

// W_in (512x1536)->WinT(1536x512) bf16 ; W_out(768x512)->WoutT(512x768) bf16 ; W_x(768x8)->WxT(8x768) f32
__global__ __launch_bounds__(256) void cvtT2_kernel(const float* __restrict__ W_in, const float* __restrict__ W_out,
                                                    const float* __restrict__ W_x,
                                                    bfu* __restrict__ WinT, bfu* __restrict__ WoutT,
                                                    float* __restrict__ WxT){
  int g = blockIdx.x * 256 + threadIdx.x;
  if (g < 786432){
    int r = g % 512, c = g / 512;
    WinT[g] = f2bf(W_in[(size_t)r * 1536 + c]);
  } else if (g < 786432 + 393216){
    int h = g - 786432;
    int r = h % 768, c = h / 768;
    WoutT[h] = f2bf(W_out[(size_t)r * 512 + c]);
  } else if (g < 786432 + 393216 + 6144){
    int h = g - (786432 + 393216);
    int n = h / 768, k = h % 768;
    WxT[h] = W_x[(size_t)k * 8 + n];
  }
}

// ---------------- MFMA GEMM: C = A(MxK) * Bt(NxK)^T ----------------
// 128x128 tile, BK=64, global_load_lds(16B), XOR-swizzled LDS (T2).
template<int EPI>
__global__ __launch_bounds__(256)
void gemm_bt(const bfu* __restrict__ Amat, const bfu* __restrict__ Bt,
             void* __restrict__ out0, void* __restrict__ out1,
             int M, int N, int K)
{
  __shared__ bfu As[128 * 64];
  __shared__ bfu Bs[128 * 64];
  const int tid  = threadIdx.x;
  const int lane = tid & 63;
  const int w    = tid >> 6;
  const int wr   = w >> 1, wc = w & 1;
  const int bn = blockIdx.x, bm = blockIdx.y;

  const int srow = w * 8 + (lane >> 3);
  const int scol = ((lane & 7) ^ (lane >> 3)) * 8;
  const bfu* gA = Amat + ((size_t)(bm * 128 + srow)) * K + scol;
  const bfu* gB = Bt   + ((size_t)(bn * 128 + srow)) * K + scol;
  bfu* lA = As + (w * 8) * 64;
  bfu* lB = Bs + (w * 8) * 64;

  f32x4 acc[4][4];
  #pragma unroll
  for (int i = 0; i < 4; i++)
    #pragma unroll
    for (int j = 0; j < 4; j++)
      #pragma unroll
      for (int r = 0; r < 4; r++) acc[i][j][r] = 0.f;

  for (int k0 = 0; k0 < K; k0 += 64){
    #pragma unroll
    for (int i = 0; i < 4; i++){
      gload16(gA + (size_t)(i * 32) * K + k0, lA + i * 32 * 64);
      gload16(gB + (size_t)(i * 32) * K + k0, lB + i * 32 * 64);
    }
    __syncthreads();

    #pragma unroll
    for (int kk = 0; kk < 2; kk++){
      short8 a[4], b[4];
      const int sA = ((kk * 4 + (lane >> 4)) ^ (lane & 7)) * 8;
      #pragma unroll
      for (int m = 0; m < 4; m++){
        int r = wr * 64 + m * 16 + (lane & 15);
        a[m] = *(const short8*)&As[r * 64 + sA];
      }
      #pragma unroll
      for (int n = 0; n < 4; n++){
        int r = wc * 64 + n * 16 + (lane & 15);
        b[n] = *(const short8*)&Bs[r * 64 + sA];
      }
      #pragma unroll
      for (int m = 0; m < 4; m++)
        #pragma unroll
        for (int n = 0; n < 4; n++)
          acc[m][n] = __builtin_amdgcn_mfma_f32_16x16x32_bf16(a[m], b[n], acc[m][n], 0, 0, 0);
    }
    __syncthreads();
  }

  #pragma unroll
  for (int m = 0; m < 4; m++){
    #pragma unroll
    for (int n = 0; n < 4; n++){
      const int row0 = bm * 128 + wr * 64 + m * 16 + (lane >> 4) * 4;
      const int col  = bn * 128 + wc * 64 + n * 16 + (lane & 15);
      #pragma unroll
      for (int r = 0; r < 4; r++){
        float v = acc[m][n][r];
        int row = row0 + r;
        if (EPI == 0){
          float s = v / (1.f + __expf(-v));   // silu
          if (col < 768) ((bfu*)out0)[(size_t)row * 768 + col]         = f2bf(s);
          else           ((bfu*)out1)[(size_t)row * 768 + (col - 768)] = f2bf(s);
        } else {
          ((float*)out0)[(size_t)row * N + col] = v;
        }
      }
    }
  }
}

// ---------------- u = xssm @ W_x  (uses WxT [8][768], coalesced) ----------------
__global__ __launch_bounds__(256) void u_kernel(const bfu* __restrict__ xssm, const float* __restrict__ WxT,
                                                float* __restrict__ u){
  int wid = threadIdx.x >> 6, lane = threadIdx.x & 63;
  int row = blockIdx.x * 4 + wid;
  const bfu* xr = xssm + (size_t)row * 768;
  float acc[8];
  #pragma unroll
  for (int n = 0; n < 8; n++) acc[n] = 0.f;
  #pragma unroll
  for (int i = 0; i < 3; i++){
    int kb = i * 256 + lane * 4;
    ushort4 xq = *(const ushort4*)(xr + kb);
    float x0 = bf2f(xq.x), x1 = bf2f(xq.y), x2 = bf2f(xq.z), x3 = bf2f(xq.w);
    #pragma unroll
    for (int n = 0; n < 8; n++){
      float4 wv = *(const float4*)(WxT + (size_t)n * 768 + kb);
      acc[n] += x0 * wv.x + x1 * wv.y + x2 * wv.z + x3 * wv.w;
    }
  }
  #pragma unroll
  for (int n = 0; n < 8; n++){
    #pragma unroll
    for (int off = 32; off >= 1; off >>= 1) acc[n] += __shfl_xor(acc[n], off, 64);
  }
  if (lane == 0){
    float4 o0 = { acc[0], acc[1], acc[2], acc[3] };
    float4 o1 = { acc[4], acc[5], acc[6], acc[7] };
    *(float4*)(u + (size_t)row * 8)     = o0;
    *(float4*)(u + (size_t)row * 8 + 4) = o1;
  }
}

// ---------------- scan phase 1: per-chunk local scan, delta inline ----------------
// grid: b(8) x c(64) x dblk(3), block 128; each thread owns 2 consecutive d
// P/H layout: [b][c][d][n]
__global__ __launch_bounds__(128) void scan_phase1(const bfu* __restrict__ xssm, const float* __restrict__ u,
    const float* __restrict__ Wdt, const float* __restrict__ bdt, const float* __restrict__ A_log,
    float* __restrict__ Pws, float* __restrict__ Hws){
  int tid = threadIdx.x;
  int bid = blockIdx.x;
  int b = bid / 192; int rem = bid % 192;
  int c = rem / 3;   int dblk = rem % 3;
  int d0 = dblk * 256 + tid * 2;
  float Al2[2][8], P[2][8], H[2][8], Wr[2][8], bd[2];
  #pragma unroll
  for (int j = 0; j < 2; j++){
    bd[j] = bdt[d0 + j];
    #pragma unroll
    for (int n = 0; n < 8; n++){
      Al2[j][n] = -__expf(A_log[(size_t)(d0 + j) * 8 + n]) * 1.4426950408889634f;
      Wr[j][n]  = Wdt[(size_t)n * 768 + d0 + j];
      P[j][n] = 1.f; H[j][n] = 0.f;
    }
  }
  int r0 = b * 2048 + c * 32;
  size_t base = (size_t)r0 * 768 + d0;
  #pragma unroll 4
  for (int i = 0; i < 32; i++){
    float4 u0 = *(const float4*)(u + (size_t)(r0 + i) * 8);
    float4 u1 = *(const float4*)(u + (size_t)(r0 + i) * 8 + 4);
    ushort2 xq = *(const ushort2*)(xssm + base + (size_t)i * 768);
    #pragma unroll
    for (int j = 0; j < 2; j++){
      float xt = bf2f(j == 0 ? xq.x : xq.y);
      float dv = bd[j] + u0.x * Wr[j][0] + u0.y * Wr[j][1] + u0.z * Wr[j][2] + u0.w * Wr[j][3]
                       + u1.x * Wr[j][4] + u1.y * Wr[j][5] + u1.z * Wr[j][6] + u1.w * Wr[j][7];
      float dt = softplusf(dv);
      float dx = dt * xt;
      #pragma unroll
      for (int n = 0; n < 8; n++){
        float e = exp2f(dt * Al2[j][n]);
        H[j][n] = e * H[j][n] + dx;
        P[j][n] *= e;
      }
    }
  }
  size_t o = (((size_t)b * 64 + c) * 768 + d0) * 8;
  #pragma unroll
  for (int j = 0; j < 2; j++){
    float4 p0 = { P[j][0], P[j][1], P[j][2], P[j][3] };
    float4 p1 = { P[j][4], P[j][5], P[j][6], P[j][7] };
    float4 h0 = { H[j][0], H[j][1], H[j][2], H[j][3] };
    float4 h1 = { H[j][4], H[j][5], H[j][6], H[j][7] };
    *(float4*)(Pws + o + j * 8)     = p0;
    *(float4*)(Pws + o + j * 8 + 4) = p1;
    *(float4*)(Hws + o + j * 8)     = h0;
    *(float4*)(Hws + o + j * 8 + 4) = h1;
  }
}

// ---------------- scan phase 2: combine chunks; Hin written IN-PLACE into Pws ----------------
__global__ __launch_bounds__(256) void scan_phase2(float* __restrict__ Pws, const float* __restrict__ Hws){
  int g = blockIdx.x * 256 + threadIdx.x;   // 49152 = 8*768*8
  int within = g % 6144;                    // d*8+n
  int b = g / 6144;
  size_t base = (size_t)b * 64 * 6144 + within;
  float hin = 0.f;
  #pragma unroll 8
  for (int c = 0; c < 64; c++){
    size_t idx = base + (size_t)c * 6144;
    float p = Pws[idx], hh = Hws[idx];
    Pws[idx] = hin;                         // h_in for chunk c
    hin = p * hin + hh;
  }
}

// ---------------- scan phase 3: re-run chunk with h_in, delta inline, fuse gate ----------------
__global__ __launch_bounds__(128) void scan_phase3(const bfu* __restrict__ xssm, const float* __restrict__ u,
    const float* __restrict__ Wdt, const float* __restrict__ bdt, const float* __restrict__ A_log,
    const float* __restrict__ Dp, const bfu* __restrict__ siluz, const float* __restrict__ Hin,
    bfu* __restrict__ yz){
  int tid = threadIdx.x;
  int bid = blockIdx.x;
  int b = bid / 192; int rem = bid % 192;
  int c = rem / 3;   int dblk = rem % 3;
  int d0 = dblk * 256 + tid * 2;
  float Al2[2][8], H[2][8], Wr[2][8], bd[2], Dd[2];
  size_t o = (((size_t)b * 64 + c) * 768 + d0) * 8;
  #pragma unroll
  for (int j = 0; j < 2; j++){
    bd[j] = bdt[d0 + j];
    Dd[j] = Dp[d0 + j];
    float4 h0 = *(const float4*)(Hin + o + j * 8);
    float4 h1 = *(const float4*)(Hin + o + j * 8 + 4);
    H[j][0] = h0.x; H[j][1] = h0.y; H[j][2] = h0.z; H[j][3] = h0.w;
    H[j][4] = h1.x; H[j][5] = h1.y; H[j][6] = h1.z; H[j][7] = h1.w;
    #pragma unroll
    for (int n = 0; n < 8; n++){
      Al2[j][n] = -__expf(A_log[(size_t)(d0 + j) * 8 + n]) * 1.4426950408889634f;
      Wr[j][n]  = Wdt[(size_t)n * 768 + d0 + j];
    }
  }
  int r0 = b * 2048 + c * 32;
  size_t base = (size_t)r0 * 768 + d0;
  #pragma unroll 4
  for (int i = 0; i < 32; i++){
    float4 u0 = *(const float4*)(u + (size_t)(r0 + i) * 8);
    float4 u1 = *(const float4*)(u + (size_t)(r0 + i) * 8 + 4);
    ushort2 xq = *(const ushort2*)(xssm + base + (size_t)i * 768);
    ushort2 zq = *(const ushort2*)(siluz + base + (size_t)i * 768);
    ushort2 oq;
    #pragma unroll
    for (int j = 0; j < 2; j++){
      float xt = bf2f(j == 0 ? xq.x : xq.y);
      float dv = bd[j] + u0.x * Wr[j][0] + u0.y * Wr[j][1] + u0.z * Wr[j][2] + u0.w * Wr[j][3]
                       + u1.x * Wr[j][4] + u1.y * Wr[j][5] + u1.z * Wr[j][6] + u1.w * Wr[j][7];
      float dt = softplusf(dv);
      float dx = dt * xt;
      float y = Dd[j] * xt;
      #pragma unroll
      for (int n = 0; n < 8; n++){
        float e = exp2f(dt * Al2[j][n]);
        H[j][n] = e * H[j][n] + dx;
        y += H[j][n];
      }
      float sz = bf2f(j == 0 ? zq.x : zq.y);
      bfu r = f2bf(y * sz);
      if (j == 0) oq.x = r; else oq.y = r;
    }
    *(ushort2*)(yz + base + (size_t)i * 768) = oq;
  }
}

extern "C" void kernel_launch(void* const* d_in, const int* in_sizes, int n_in,
                              void* d_out, int out_size, void* d_ws, size_t ws_size,
                              hipStream_t stream){
  const float* x     = (const float*)d_in[0];
  const float* W_in  = (const float*)d_in[1];
  const float* A_log = (const float*)d_in[2];
  const float* D_par = (const float*)d_in[3];
  const float* W_x   = (const float*)d_in[4];
  const float* W_dt  = (const float*)d_in[5];
  const float* b_dt  = (const float*)d_in[6];
  const float* W_out = (const float*)d_in[7];
  float* out = (float*)d_out;
  (void)in_sizes; (void)n_in; (void)out_size; (void)ws_size;

  char* base = (char*)d_ws;
  size_t off = 0;
  auto alloc = [&](size_t bytes)->char*{
    char* p = base + off; off += (bytes + 255) & ~(size_t)255; return p;
  };
  bfu*   x_bf  = (bfu*)  alloc((size_t)16384 * 512 * 2);
  bfu*   WinT  = (bfu*)  alloc((size_t)1536 * 512 * 2);
  bfu*   WoutT = (bfu*)  alloc((size_t)512 * 768 * 2);
  float* WxT   = (float*)alloc((size_t)8 * 768 * 4);
  bfu*   xssm  = (bfu*)  alloc((size_t)16384 * 768 * 2);
  bfu*   siluz = (bfu*)  alloc((size_t)16384 * 768 * 2);
  float* u     = (float*)alloc((size_t)16384 * 8 * 4);
  float* Pws   = (float*)alloc((size_t)8 * 64 * 768 * 8 * 4);
  float* Hws   = (float*)alloc((size_t)8 * 64 * 768 * 8 * 4);
  bfu*   yz    = (bfu*)  alloc((size_t)16384 * 768 * 2);

  // 1) convert x to bf16
  cvt4_kernel<<<8192, 256, 0, stream>>>(x, x_bf, 2097152);
  // 2) transpose+convert weights (+ WxT)
  cvtT2_kernel<<<4632, 256, 0, stream>>>(W_in, W_out, W_x, WinT, WoutT, WxT);
  // 3) GEMM1: xz = x @ W_in, fused silu + split -> xssm, siluz (bf16)
  gemm_bt<0><<<dim3(12, 128), 256, 0, stream>>>(x_bf, WinT, xssm, siluz, 16384, 1536, 512);
  // 4) u = xssm @ W_x
  u_kernel<<<4096, 256, 0, stream>>>(xssm, WxT, u);
  // 5-7) chunked scan (delta recomputed inline from u)
  scan_phase1<<<1536, 128, 0, stream>>>(xssm, u, W_dt, b_dt, A_log, Pws, Hws);
  scan_phase2<<<192, 256, 0, stream>>>(Pws, Hws);
  scan_phase3<<<1536, 128, 0, stream>>>(xssm, u, W_dt, b_dt, A_log, D_par, siluz, Pws, yz);
  // 8) out = yz @ W_out (f32 out)
  gemm_bt<1><<<dim3(4, 128), 256, 0, stream>>>(yz, WoutT, out, nullptr, 16384, 512, 768);
}

// Round 4
// 174.873 us; speedup vs baseline: 1.5540x; 1.1519x over previous
//
#include <hip/hip_runtime.h>

typedef unsigned short bfu;
typedef __attribute__((ext_vector_type(8))) short short8;
typedef __attribute__((ext_vector_type(4))) float f32x4;

__device__ __forceinline__ float bf2f(bfu u){
  union { unsigned int i; float f; } v; v.i = ((unsigned int)u) << 16; return v.f;
}
__device__ __forceinline__ bfu f2bf(float f){
  union { float f; unsigned int i; } v; v.f = f;
  unsigned int r = (v.i + 0x7FFFu + ((v.i >> 16) & 1u)) >> 16;
  return (bfu)r;
}
// raw HW transcendentals (v_exp_f32 / v_log_f32); denormal flush is fine here
__device__ __forceinline__ float fexp2(float x){ return __builtin_amdgcn_exp2f(x); }
__device__ __forceinline__ float flog2(float x){ return __builtin_amdgcn_logf(x); }
// fast softplus: max(x,0) + ln2*log2(1+exp2(-|x|*log2e)) ; 6 VALU + 2 trans
__device__ __forceinline__ float softplusf(float x){
  float t = fexp2(-fabsf(x) * 1.44269504088896f);
  return fmaxf(x, 0.f) + 0.69314718055995f * flog2(1.f + t);
}
__device__ __forceinline__ void gload16(const bfu* g, bfu* l){
  __builtin_amdgcn_global_load_lds((const __attribute__((address_space(1))) unsigned int*)g,
                                   (__attribute__((address_space(3))) unsigned int*)l, 16, 0, 0);
}

// ---------------- conversion kernels ----------------
__global__ __launch_bounds__(256) void cvt4_kernel(const float* __restrict__ in, bfu* __restrict__ out, int n4){
  int g = blockIdx.x * 256 + threadIdx.x;
  if (g < n4){
    float4 v = ((const float4*)in)[g];
    ushort4 o;
    o.x = f2bf(v.x); o.y = f2bf(v.y); o.z = f2bf(v.z); o.w = f2bf(v.w);
    ((ushort4*)out)[g] = o;
  }
}

// W_in (512x1536)->WinT(1536x512) bf16 ; W_out(768x512)->WoutT(512x768) bf16 ; W_x(768x8)->WxT(8x768) f32
__global__ __launch_bounds__(256) void cvtT2_kernel(const float* __restrict__ W_in, const float* __restrict__ W_out,
                                                    const float* __restrict__ W_x,
                                                    bfu* __restrict__ WinT, bfu* __restrict__ WoutT,
                                                    float* __restrict__ WxT){
  int g = blockIdx.x * 256 + threadIdx.x;
  if (g < 786432){
    int r = g % 512, c = g / 512;
    WinT[g] = f2bf(W_in[(size_t)r * 1536 + c]);
  } else if (g < 786432 + 393216){
    int h = g - 786432;
    int r = h % 768, c = h / 768;
    WoutT[h] = f2bf(W_out[(size_t)r * 512 + c]);
  } else if (g < 786432 + 393216 + 6144){
    int h = g - (786432 + 393216);
    int n = h / 768, k = h % 768;
    WxT[h] = W_x[(size_t)k * 8 + n];
  }
}

// ---------------- MFMA GEMM: C = A(MxK) * Bt(NxK)^T ----------------
// 128x128 tile, BK=64, global_load_lds(16B), XOR-swizzled LDS (T2).
template<int EPI>
__global__ __launch_bounds__(256)
void gemm_bt(const bfu* __restrict__ Amat, const bfu* __restrict__ Bt,
             void* __restrict__ out0, void* __restrict__ out1,
             int M, int N, int K)
{
  __shared__ bfu As[128 * 64];
  __shared__ bfu Bs[128 * 64];
  const int tid  = threadIdx.x;
  const int lane = tid & 63;
  const int w    = tid >> 6;
  const int wr   = w >> 1, wc = w & 1;
  const int bn = blockIdx.x, bm = blockIdx.y;

  const int srow = w * 8 + (lane >> 3);
  const int scol = ((lane & 7) ^ (lane >> 3)) * 8;
  const bfu* gA = Amat + ((size_t)(bm * 128 + srow)) * K + scol;
  const bfu* gB = Bt   + ((size_t)(bn * 128 + srow)) * K + scol;
  bfu* lA = As + (w * 8) * 64;
  bfu* lB = Bs + (w * 8) * 64;

  f32x4 acc[4][4];
  #pragma unroll
  for (int i = 0; i < 4; i++)
    #pragma unroll
    for (int j = 0; j < 4; j++)
      #pragma unroll
      for (int r = 0; r < 4; r++) acc[i][j][r] = 0.f;

  for (int k0 = 0; k0 < K; k0 += 64){
    #pragma unroll
    for (int i = 0; i < 4; i++){
      gload16(gA + (size_t)(i * 32) * K + k0, lA + i * 32 * 64);
      gload16(gB + (size_t)(i * 32) * K + k0, lB + i * 32 * 64);
    }
    __syncthreads();

    #pragma unroll
    for (int kk = 0; kk < 2; kk++){
      short8 a[4], b[4];
      const int sA = ((kk * 4 + (lane >> 4)) ^ (lane & 7)) * 8;
      #pragma unroll
      for (int m = 0; m < 4; m++){
        int r = wr * 64 + m * 16 + (lane & 15);
        a[m] = *(const short8*)&As[r * 64 + sA];
      }
      #pragma unroll
      for (int n = 0; n < 4; n++){
        int r = wc * 64 + n * 16 + (lane & 15);
        b[n] = *(const short8*)&Bs[r * 64 + sA];
      }
      #pragma unroll
      for (int m = 0; m < 4; m++)
        #pragma unroll
        for (int n = 0; n < 4; n++)
          acc[m][n] = __builtin_amdgcn_mfma_f32_16x16x32_bf16(a[m], b[n], acc[m][n], 0, 0, 0);
    }
    __syncthreads();
  }

  #pragma unroll
  for (int m = 0; m < 4; m++){
    #pragma unroll
    for (int n = 0; n < 4; n++){
      const int row0 = bm * 128 + wr * 64 + m * 16 + (lane >> 4) * 4;
      const int col  = bn * 128 + wc * 64 + n * 16 + (lane & 15);
      #pragma unroll
      for (int r = 0; r < 4; r++){
        float v = acc[m][n][r];
        int row = row0 + r;
        if (EPI == 0){
          float s = v / (1.f + __expf(-v));   // silu
          if (col < 768) ((bfu*)out0)[(size_t)row * 768 + col]         = f2bf(s);
          else           ((bfu*)out1)[(size_t)row * 768 + (col - 768)] = f2bf(s);
        } else {
          ((float*)out0)[(size_t)row * N + col] = v;
        }
      }
    }
  }
}

// ---------------- u = xssm @ W_x  (uses WxT [8][768], coalesced) ----------------
__global__ __launch_bounds__(256) void u_kernel(const bfu* __restrict__ xssm, const float* __restrict__ WxT,
                                                float* __restrict__ u){
  int wid = threadIdx.x >> 6, lane = threadIdx.x & 63;
  int row = blockIdx.x * 4 + wid;
  const bfu* xr = xssm + (size_t)row * 768;
  float acc[8];
  #pragma unroll
  for (int n = 0; n < 8; n++) acc[n] = 0.f;
  #pragma unroll
  for (int i = 0; i < 3; i++){
    int kb = i * 256 + lane * 4;
    ushort4 xq = *(const ushort4*)(xr + kb);
    float x0 = bf2f(xq.x), x1 = bf2f(xq.y), x2 = bf2f(xq.z), x3 = bf2f(xq.w);
    #pragma unroll
    for (int n = 0; n < 8; n++){
      float4 wv = *(const float4*)(WxT + (size_t)n * 768 + kb);
      acc[n] += x0 * wv.x + x1 * wv.y + x2 * wv.z + x3 * wv.w;
    }
  }
  #pragma unroll
  for (int n = 0; n < 8; n++){
    #pragma unroll
    for (int off = 32; off >= 1; off >>= 1) acc[n] += __shfl_xor(acc[n], off, 64);
  }
  if (lane == 0){
    float4 o0 = { acc[0], acc[1], acc[2], acc[3] };
    float4 o1 = { acc[4], acc[5], acc[6], acc[7] };
    *(float4*)(u + (size_t)row * 8)     = o0;
    *(float4*)(u + (size_t)row * 8 + 4) = o1;
  }
}

// ---------------- scan phase 1: per-chunk local scan, delta inline ----------------
// grid: b(8) x c(64) x dblk(3), block 128; each thread owns 2 consecutive d
// P/H layout: [b][c][d][n].  P computed as exp2(Al2*sum(dt)) at chunk end.
__global__ __launch_bounds__(128) void scan_phase1(const bfu* __restrict__ xssm, const float* __restrict__ u,
    const float* __restrict__ Wdt, const float* __restrict__ bdt, const float* __restrict__ A_log,
    float* __restrict__ Pws, float* __restrict__ Hws){
  int tid = threadIdx.x;
  int bid = blockIdx.x;
  int b = bid / 192; int rem = bid % 192;
  int c = rem / 3;   int dblk = rem % 3;
  int d0 = dblk * 256 + tid * 2;
  float Al2[2][8], H[2][8], Wr[2][8], bd[2], S[2];
  #pragma unroll
  for (int j = 0; j < 2; j++){
    bd[j] = bdt[d0 + j];
    S[j] = 0.f;
    #pragma unroll
    for (int n = 0; n < 8; n++){
      Al2[j][n] = -__expf(A_log[(size_t)(d0 + j) * 8 + n]) * 1.4426950408889634f;
      Wr[j][n]  = Wdt[(size_t)n * 768 + d0 + j];
      H[j][n] = 0.f;
    }
  }
  int r0 = b * 2048 + c * 32;
  size_t base = (size_t)r0 * 768 + d0;
  #pragma unroll 8
  for (int i = 0; i < 32; i++){
    float4 u0 = *(const float4*)(u + (size_t)(r0 + i) * 8);
    float4 u1 = *(const float4*)(u + (size_t)(r0 + i) * 8 + 4);
    ushort2 xq = *(const ushort2*)(xssm + base + (size_t)i * 768);
    #pragma unroll
    for (int j = 0; j < 2; j++){
      float xt = bf2f(j == 0 ? xq.x : xq.y);
      float dv = bd[j] + u0.x * Wr[j][0] + u0.y * Wr[j][1] + u0.z * Wr[j][2] + u0.w * Wr[j][3]
                       + u1.x * Wr[j][4] + u1.y * Wr[j][5] + u1.z * Wr[j][6] + u1.w * Wr[j][7];
      float dt = softplusf(dv);
      float dx = dt * xt;
      S[j] += dt;
      #pragma unroll
      for (int n = 0; n < 8; n++){
        float e = fexp2(dt * Al2[j][n]);
        H[j][n] = e * H[j][n] + dx;
      }
    }
  }
  size_t o = (((size_t)b * 64 + c) * 768 + d0) * 8;
  #pragma unroll
  for (int j = 0; j < 2; j++){
    float4 p0, p1;
    p0.x = fexp2(S[j] * Al2[j][0]); p0.y = fexp2(S[j] * Al2[j][1]);
    p0.z = fexp2(S[j] * Al2[j][2]); p0.w = fexp2(S[j] * Al2[j][3]);
    p1.x = fexp2(S[j] * Al2[j][4]); p1.y = fexp2(S[j] * Al2[j][5]);
    p1.z = fexp2(S[j] * Al2[j][6]); p1.w = fexp2(S[j] * Al2[j][7]);
    float4 h0 = { H[j][0], H[j][1], H[j][2], H[j][3] };
    float4 h1 = { H[j][4], H[j][5], H[j][6], H[j][7] };
    *(float4*)(Pws + o + j * 8)     = p0;
    *(float4*)(Pws + o + j * 8 + 4) = p1;
    *(float4*)(Hws + o + j * 8)     = h0;
    *(float4*)(Hws + o + j * 8 + 4) = h1;
  }
}

// ---------------- scan phase 2: combine chunks; Hin written IN-PLACE into Pws ----------------
__global__ __launch_bounds__(256) void scan_phase2(float* __restrict__ Pws, const float* __restrict__ Hws){
  int g = blockIdx.x * 256 + threadIdx.x;   // 49152 = 8*768*8
  int within = g % 6144;                    // d*8+n
  int b = g / 6144;
  size_t base = (size_t)b * 64 * 6144 + within;
  float hin = 0.f;
  #pragma unroll 8
  for (int c = 0; c < 64; c++){
    size_t idx = base + (size_t)c * 6144;
    float p = Pws[idx], hh = Hws[idx];
    Pws[idx] = hin;                         // h_in for chunk c
    hin = p * hin + hh;
  }
}

// ---------------- scan phase 3: re-run chunk with h_in, delta inline, fuse gate ----------------
__global__ __launch_bounds__(128) void scan_phase3(const bfu* __restrict__ xssm, const float* __restrict__ u,
    const float* __restrict__ Wdt, const float* __restrict__ bdt, const float* __restrict__ A_log,
    const float* __restrict__ Dp, const bfu* __restrict__ siluz, const float* __restrict__ Hin,
    bfu* __restrict__ yz){
  int tid = threadIdx.x;
  int bid = blockIdx.x;
  int b = bid / 192; int rem = bid % 192;
  int c = rem / 3;   int dblk = rem % 3;
  int d0 = dblk * 256 + tid * 2;
  float Al2[2][8], H[2][8], Wr[2][8], bd[2], Dd[2];
  size_t o = (((size_t)b * 64 + c) * 768 + d0) * 8;
  #pragma unroll
  for (int j = 0; j < 2; j++){
    bd[j] = bdt[d0 + j];
    Dd[j] = Dp[d0 + j];
    float4 h0 = *(const float4*)(Hin + o + j * 8);
    float4 h1 = *(const float4*)(Hin + o + j * 8 + 4);
    H[j][0] = h0.x; H[j][1] = h0.y; H[j][2] = h0.z; H[j][3] = h0.w;
    H[j][4] = h1.x; H[j][5] = h1.y; H[j][6] = h1.z; H[j][7] = h1.w;
    #pragma unroll
    for (int n = 0; n < 8; n++){
      Al2[j][n] = -__expf(A_log[(size_t)(d0 + j) * 8 + n]) * 1.4426950408889634f;
      Wr[j][n]  = Wdt[(size_t)n * 768 + d0 + j];
    }
  }
  int r0 = b * 2048 + c * 32;
  size_t base = (size_t)r0 * 768 + d0;
  #pragma unroll 8
  for (int i = 0; i < 32; i++){
    float4 u0 = *(const float4*)(u + (size_t)(r0 + i) * 8);
    float4 u1 = *(const float4*)(u + (size_t)(r0 + i) * 8 + 4);
    ushort2 xq = *(const ushort2*)(xssm + base + (size_t)i * 768);
    ushort2 zq = *(const ushort2*)(siluz + base + (size_t)i * 768);
    ushort2 oq;
    #pragma unroll
    for (int j = 0; j < 2; j++){
      float xt = bf2f(j == 0 ? xq.x : xq.y);
      float dv = bd[j] + u0.x * Wr[j][0] + u0.y * Wr[j][1] + u0.z * Wr[j][2] + u0.w * Wr[j][3]
                       + u1.x * Wr[j][4] + u1.y * Wr[j][5] + u1.z * Wr[j][6] + u1.w * Wr[j][7];
      float dt = softplusf(dv);
      float dx = dt * xt;
      float y = Dd[j] * xt;
      #pragma unroll
      for (int n = 0; n < 8; n++){
        float e = fexp2(dt * Al2[j][n]);
        H[j][n] = e * H[j][n] + dx;
        y += H[j][n];
      }
      float sz = bf2f(j == 0 ? zq.x : zq.y);
      bfu r = f2bf(y * sz);
      if (j == 0) oq.x = r; else oq.y = r;
    }
    *(ushort2*)(yz + base + (size_t)i * 768) = oq;
  }
}

extern "C" void kernel_launch(void* const* d_in, const int* in_sizes, int n_in,
                              void* d_out, int out_size, void* d_ws, size_t ws_size,
                              hipStream_t stream){
  const float* x     = (const float*)d_in[0];
  const float* W_in  = (const float*)d_in[1];
  const float* A_log = (const float*)d_in[2];
  const float* D_par = (const float*)d_in[3];
  const float* W_x   = (const float*)d_in[4];
  const float* W_dt  = (const float*)d_in[5];
  const float* b_dt  = (const float*)d_in[6];
  const float* W_out = (const float*)d_in[7];
  float* out = (float*)d_out;
  (void)in_sizes; (void)n_in; (void)out_size; (void)ws_size;

  char* base = (char*)d_ws;
  size_t off = 0;
  auto alloc = [&](size_t bytes)->char*{
    char* p = base + off; off += (bytes + 255) & ~(size_t)255; return p;
  };
  bfu*   x_bf  = (bfu*)  alloc((size_t)16384 * 512 * 2);
  bfu*   WinT  = (bfu*)  alloc((size_t)1536 * 512 * 2);
  bfu*   WoutT = (bfu*)  alloc((size_t)512 * 768 * 2);
  float* WxT   = (float*)alloc((size_t)8 * 768 * 4);
  bfu*   xssm  = (bfu*)  alloc((size_t)16384 * 768 * 2);
  bfu*   siluz = (bfu*)  alloc((size_t)16384 * 768 * 2);
  float* u     = (float*)alloc((size_t)16384 * 8 * 4);
  float* Pws   = (float*)alloc((size_t)8 * 64 * 768 * 8 * 4);
  float* Hws   = (float*)alloc((size_t)8 * 64 * 768 * 8 * 4);
  bfu*   yz    = (bfu*)  alloc((size_t)16384 * 768 * 2);

  // 1) convert x to bf16
  cvt4_kernel<<<8192, 256, 0, stream>>>(x, x_bf, 2097152);
  // 2) transpose+convert weights (+ WxT)
  cvtT2_kernel<<<4632, 256, 0, stream>>>(W_in, W_out, W_x, WinT, WoutT, WxT);
  // 3) GEMM1: xz = x @ W_in, fused silu + split -> xssm, siluz (bf16)
  gemm_bt<0><<<dim3(12, 128), 256, 0, stream>>>(x_bf, WinT, xssm, siluz, 16384, 1536, 512);
  // 4) u = xssm @ W_x
  u_kernel<<<4096, 256, 0, stream>>>(xssm, WxT, u);
  // 5-7) chunked scan (delta recomputed inline from u)
  scan_phase1<<<1536, 128, 0, stream>>>(xssm, u, W_dt, b_dt, A_log, Pws, Hws);
  scan_phase2<<<192, 256, 0, stream>>>(Pws, Hws);
  scan_phase3<<<1536, 128, 0, stream>>>(xssm, u, W_dt, b_dt, A_log, D_par, siluz, Pws, yz);
  // 8) out = yz @ W_out (f32 out)
  gemm_bt<1><<<dim3(4, 128), 256, 0, stream>>>(yz, WoutT, out, nullptr, 16384, 512, 768);
}

// Round 5
// 170.571 us; speedup vs baseline: 1.5932x; 1.0252x over previous
//
#include <hip/hip_runtime.h>

typedef unsigned short bfu;
typedef __attribute__((ext_vector_type(8))) short short8;
typedef __attribute__((ext_vector_type(4))) float f32x4;

__device__ __forceinline__ float bf2f(bfu u){
  union { unsigned int i; float f; } v; v.i = ((unsigned int)u) << 16; return v.f;
}
__device__ __forceinline__ bfu f2bf(float f){
  union { float f; unsigned int i; } v; v.f = f;
  unsigned int r = (v.i + 0x7FFFu + ((v.i >> 16) & 1u)) >> 16;
  return (bfu)r;
}
// raw HW transcendentals (v_exp_f32 / v_log_f32); denormal flush is fine here
__device__ __forceinline__ float fexp2(float x){ return __builtin_amdgcn_exp2f(x); }
__device__ __forceinline__ float flog2(float x){ return __builtin_amdgcn_logf(x); }
// fast softplus: max(x,0) + ln2*log2(1+exp2(-|x|*log2e)) ; 6 VALU + 2 trans
__device__ __forceinline__ float softplusf(float x){
  float t = fexp2(-fabsf(x) * 1.44269504088896f);
  return fmaxf(x, 0.f) + 0.69314718055995f * flog2(1.f + t);
}
__device__ __forceinline__ void gload16(const bfu* g, bfu* l){
  __builtin_amdgcn_global_load_lds((const __attribute__((address_space(1))) unsigned int*)g,
                                   (__attribute__((address_space(3))) unsigned int*)l, 16, 0, 0);
}

// ---------------- conversion kernels ----------------
__global__ __launch_bounds__(256) void cvt4_kernel(const float* __restrict__ in, bfu* __restrict__ out, int n4){
  int g = blockIdx.x * 256 + threadIdx.x;
  if (g < n4){
    float4 v = ((const float4*)in)[g];
    ushort4 o;
    o.x = f2bf(v.x); o.y = f2bf(v.y); o.z = f2bf(v.z); o.w = f2bf(v.w);
    ((ushort4*)out)[g] = o;
  }
}

// W_in (512x1536)->WinT(1536x512) bf16 ; W_out(768x512)->WoutT(512x768) bf16 ; W_x(768x8)->WxT(8x768) f32
__global__ __launch_bounds__(256) void cvtT2_kernel(const float* __restrict__ W_in, const float* __restrict__ W_out,
                                                    const float* __restrict__ W_x,
                                                    bfu* __restrict__ WinT, bfu* __restrict__ WoutT,
                                                    float* __restrict__ WxT){
  int g = blockIdx.x * 256 + threadIdx.x;
  if (g < 786432){
    int r = g % 512, c = g / 512;
    WinT[g] = f2bf(W_in[(size_t)r * 1536 + c]);
  } else if (g < 786432 + 393216){
    int h = g - 786432;
    int r = h % 768, c = h / 768;
    WoutT[h] = f2bf(W_out[(size_t)r * 512 + c]);
  } else if (g < 786432 + 393216 + 6144){
    int h = g - (786432 + 393216);
    int n = h / 768, k = h % 768;
    WxT[h] = W_x[(size_t)k * 8 + n];
  }
}

// ---------------- MFMA GEMM: C = A(MxK) * Bt(NxK)^T ----------------
// BM=256, BN=128, BK=64, 512 threads (8 waves, 4M x 2N), XCD-swizzled blocks,
// global_load_lds(16B), XOR-swizzled LDS (T2).  NBN = N/128 passed as param.
template<int EPI>
__global__ __launch_bounds__(512)
void gemm_big(const bfu* __restrict__ Amat, const bfu* __restrict__ Bt,
              void* __restrict__ out0, void* __restrict__ out1,
              int NBN, int N, int K)
{
  __shared__ bfu As[256 * 64];
  __shared__ bfu Bs[128 * 64];
  const int tid  = threadIdx.x;
  const int lane = tid & 63;
  const int w    = tid >> 6;
  const int wr   = w >> 1, wc = w & 1;   // 4 x 2 wave grid

  // XCD-aware bijective swizzle (nwg % 8 == 0)
  const int cpx = gridDim.x >> 3;
  const int id  = blockIdx.x;
  const int nid = (id & 7) * cpx + (id >> 3);
  const int bn  = nid % NBN;
  const int bm  = nid / NBN;

  // staging: thread t covers row (t>>3) of each 64-row issue group, slot t&7
  const int srow = tid >> 3;             // 0..63
  const int scol = ((tid & 7) ^ (srow & 7)) * 8;   // pre-swizzled global col
  const bfu* gA = Amat + ((size_t)(bm * 256 + srow)) * K + scol;
  const bfu* gB = Bt   + ((size_t)(bn * 128 + srow)) * K + scol;
  bfu* lA = As + srow * 64 + (tid & 7) * 8;
  bfu* lB = Bs + srow * 64 + (tid & 7) * 8;

  f32x4 acc[4][4];
  #pragma unroll
  for (int i = 0; i < 4; i++)
    #pragma unroll
    for (int j = 0; j < 4; j++)
      #pragma unroll
      for (int r = 0; r < 4; r++) acc[i][j][r] = 0.f;

  for (int k0 = 0; k0 < K; k0 += 64){
    #pragma unroll
    for (int i = 0; i < 4; i++)
      gload16(gA + (size_t)(i * 64) * K + k0, lA + i * 64 * 64);
    #pragma unroll
    for (int i = 0; i < 2; i++)
      gload16(gB + (size_t)(i * 64) * K + k0, lB + i * 64 * 64);
    __syncthreads();

    #pragma unroll
    for (int kk = 0; kk < 2; kk++){
      short8 a[4], b[4];
      const int sA = ((kk * 4 + (lane >> 4)) ^ (lane & 7)) * 8;
      #pragma unroll
      for (int m = 0; m < 4; m++){
        int r = wr * 64 + m * 16 + (lane & 15);
        a[m] = *(const short8*)&As[r * 64 + sA];
      }
      #pragma unroll
      for (int n = 0; n < 4; n++){
        int r = wc * 64 + n * 16 + (lane & 15);
        b[n] = *(const short8*)&Bs[r * 64 + sA];
      }
      #pragma unroll
      for (int m = 0; m < 4; m++)
        #pragma unroll
        for (int n = 0; n < 4; n++)
          acc[m][n] = __builtin_amdgcn_mfma_f32_16x16x32_bf16(a[m], b[n], acc[m][n], 0, 0, 0);
    }
    __syncthreads();
  }

  #pragma unroll
  for (int m = 0; m < 4; m++){
    #pragma unroll
    for (int n = 0; n < 4; n++){
      const int row0 = bm * 256 + wr * 64 + m * 16 + (lane >> 4) * 4;
      const int col  = bn * 128 + wc * 64 + n * 16 + (lane & 15);
      #pragma unroll
      for (int r = 0; r < 4; r++){
        float v = acc[m][n][r];
        int row = row0 + r;
        if (EPI == 0){
          float s = v / (1.f + __expf(-v));   // silu
          if (col < 768) ((bfu*)out0)[(size_t)row * 768 + col]         = f2bf(s);
          else           ((bfu*)out1)[(size_t)row * 768 + (col - 768)] = f2bf(s);
        } else {
          ((float*)out0)[(size_t)row * N + col] = v;
        }
      }
    }
  }
}

// ---------------- u = xssm @ W_x  (uses WxT [8][768], coalesced) ----------------
__global__ __launch_bounds__(256) void u_kernel(const bfu* __restrict__ xssm, const float* __restrict__ WxT,
                                                float* __restrict__ u){
  int wid = threadIdx.x >> 6, lane = threadIdx.x & 63;
  int row = blockIdx.x * 4 + wid;
  const bfu* xr = xssm + (size_t)row * 768;
  float acc[8];
  #pragma unroll
  for (int n = 0; n < 8; n++) acc[n] = 0.f;
  #pragma unroll
  for (int i = 0; i < 3; i++){
    int kb = i * 256 + lane * 4;
    ushort4 xq = *(const ushort4*)(xr + kb);
    float x0 = bf2f(xq.x), x1 = bf2f(xq.y), x2 = bf2f(xq.z), x3 = bf2f(xq.w);
    #pragma unroll
    for (int n = 0; n < 8; n++){
      float4 wv = *(const float4*)(WxT + (size_t)n * 768 + kb);
      acc[n] += x0 * wv.x + x1 * wv.y + x2 * wv.z + x3 * wv.w;
    }
  }
  #pragma unroll
  for (int n = 0; n < 8; n++){
    #pragma unroll
    for (int off = 32; off >= 1; off >>= 1) acc[n] += __shfl_xor(acc[n], off, 64);
  }
  if (lane == 0){
    float4 o0 = { acc[0], acc[1], acc[2], acc[3] };
    float4 o1 = { acc[4], acc[5], acc[6], acc[7] };
    *(float4*)(u + (size_t)row * 8)     = o0;
    *(float4*)(u + (size_t)row * 8 + 4) = o1;
  }
}

// ---------------- scan phase 1: per-chunk local scan, delta inline ----------------
__global__ __launch_bounds__(128) void scan_phase1(const bfu* __restrict__ xssm, const float* __restrict__ u,
    const float* __restrict__ Wdt, const float* __restrict__ bdt, const float* __restrict__ A_log,
    float* __restrict__ Pws, float* __restrict__ Hws){
  int tid = threadIdx.x;
  int bid = blockIdx.x;
  int b = bid / 192; int rem = bid % 192;
  int c = rem / 3;   int dblk = rem % 3;
  int d0 = dblk * 256 + tid * 2;
  float Al2[2][8], H[2][8], Wr[2][8], bd[2], S[2];
  #pragma unroll
  for (int j = 0; j < 2; j++){
    bd[j] = bdt[d0 + j];
    S[j] = 0.f;
    #pragma unroll
    for (int n = 0; n < 8; n++){
      Al2[j][n] = -__expf(A_log[(size_t)(d0 + j) * 8 + n]) * 1.4426950408889634f;
      Wr[j][n]  = Wdt[(size_t)n * 768 + d0 + j];
      H[j][n] = 0.f;
    }
  }
  int r0 = b * 2048 + c * 32;
  size_t base = (size_t)r0 * 768 + d0;
  #pragma unroll 8
  for (int i = 0; i < 32; i++){
    float4 u0 = *(const float4*)(u + (size_t)(r0 + i) * 8);
    float4 u1 = *(const float4*)(u + (size_t)(r0 + i) * 8 + 4);
    ushort2 xq = *(const ushort2*)(xssm + base + (size_t)i * 768);
    #pragma unroll
    for (int j = 0; j < 2; j++){
      float xt = bf2f(j == 0 ? xq.x : xq.y);
      float dv = bd[j] + u0.x * Wr[j][0] + u0.y * Wr[j][1] + u0.z * Wr[j][2] + u0.w * Wr[j][3]
                       + u1.x * Wr[j][4] + u1.y * Wr[j][5] + u1.z * Wr[j][6] + u1.w * Wr[j][7];
      float dt = softplusf(dv);
      float dx = dt * xt;
      S[j] += dt;
      #pragma unroll
      for (int n = 0; n < 8; n++){
        float e = fexp2(dt * Al2[j][n]);
        H[j][n] = e * H[j][n] + dx;
      }
    }
  }
  size_t o = (((size_t)b * 64 + c) * 768 + d0) * 8;
  #pragma unroll
  for (int j = 0; j < 2; j++){
    float4 p0, p1;
    p0.x = fexp2(S[j] * Al2[j][0]); p0.y = fexp2(S[j] * Al2[j][1]);
    p0.z = fexp2(S[j] * Al2[j][2]); p0.w = fexp2(S[j] * Al2[j][3]);
    p1.x = fexp2(S[j] * Al2[j][4]); p1.y = fexp2(S[j] * Al2[j][5]);
    p1.z = fexp2(S[j] * Al2[j][6]); p1.w = fexp2(S[j] * Al2[j][7]);
    float4 h0 = { H[j][0], H[j][1], H[j][2], H[j][3] };
    float4 h1 = { H[j][4], H[j][5], H[j][6], H[j][7] };
    *(float4*)(Pws + o + j * 8)     = p0;
    *(float4*)(Pws + o + j * 8 + 4) = p1;
    *(float4*)(Hws + o + j * 8)     = h0;
    *(float4*)(Hws + o + j * 8 + 4) = h1;
  }
}

// ---------------- scan phase 2: combine chunks; Hin written IN-PLACE into Pws ----------------
__global__ __launch_bounds__(256) void scan_phase2(float* __restrict__ Pws, const float* __restrict__ Hws){
  int g = blockIdx.x * 256 + threadIdx.x;   // 49152 = 8*768*8
  int within = g % 6144;                    // d*8+n
  int b = g / 6144;
  size_t base = (size_t)b * 64 * 6144 + within;
  float hin = 0.f;
  #pragma unroll 8
  for (int c = 0; c < 64; c++){
    size_t idx = base + (size_t)c * 6144;
    float p = Pws[idx], hh = Hws[idx];
    Pws[idx] = hin;                         // h_in for chunk c
    hin = p * hin + hh;
  }
}

// ---------------- scan phase 3: re-run chunk with h_in, delta inline, fuse gate ----------------
__global__ __launch_bounds__(128) void scan_phase3(const bfu* __restrict__ xssm, const float* __restrict__ u,
    const float* __restrict__ Wdt, const float* __restrict__ bdt, const float* __restrict__ A_log,
    const float* __restrict__ Dp, const bfu* __restrict__ siluz, const float* __restrict__ Hin,
    bfu* __restrict__ yz){
  int tid = threadIdx.x;
  int bid = blockIdx.x;
  int b = bid / 192; int rem = bid % 192;
  int c = rem / 3;   int dblk = rem % 3;
  int d0 = dblk * 256 + tid * 2;
  float Al2[2][8], H[2][8], Wr[2][8], bd[2], Dd[2];
  size_t o = (((size_t)b * 64 + c) * 768 + d0) * 8;
  #pragma unroll
  for (int j = 0; j < 2; j++){
    bd[j] = bdt[d0 + j];
    Dd[j] = Dp[d0 + j];
    float4 h0 = *(const float4*)(Hin + o + j * 8);
    float4 h1 = *(const float4*)(Hin + o + j * 8 + 4);
    H[j][0] = h0.x; H[j][1] = h0.y; H[j][2] = h0.z; H[j][3] = h0.w;
    H[j][4] = h1.x; H[j][5] = h1.y; H[j][6] = h1.z; H[j][7] = h1.w;
    #pragma unroll
    for (int n = 0; n < 8; n++){
      Al2[j][n] = -__expf(A_log[(size_t)(d0 + j) * 8 + n]) * 1.4426950408889634f;
      Wr[j][n]  = Wdt[(size_t)n * 768 + d0 + j];
    }
  }
  int r0 = b * 2048 + c * 32;
  size_t base = (size_t)r0 * 768 + d0;
  #pragma unroll 8
  for (int i = 0; i < 32; i++){
    float4 u0 = *(const float4*)(u + (size_t)(r0 + i) * 8);
    float4 u1 = *(const float4*)(u + (size_t)(r0 + i) * 8 + 4);
    ushort2 xq = *(const ushort2*)(xssm + base + (size_t)i * 768);
    ushort2 zq = *(const ushort2*)(siluz + base + (size_t)i * 768);
    ushort2 oq;
    #pragma unroll
    for (int j = 0; j < 2; j++){
      float xt = bf2f(j == 0 ? xq.x : xq.y);
      float dv = bd[j] + u0.x * Wr[j][0] + u0.y * Wr[j][1] + u0.z * Wr[j][2] + u0.w * Wr[j][3]
                       + u1.x * Wr[j][4] + u1.y * Wr[j][5] + u1.z * Wr[j][6] + u1.w * Wr[j][7];
      float dt = softplusf(dv);
      float dx = dt * xt;
      float y = Dd[j] * xt;
      #pragma unroll
      for (int n = 0; n < 8; n++){
        float e = fexp2(dt * Al2[j][n]);
        H[j][n] = e * H[j][n] + dx;
        y += H[j][n];
      }
      float sz = bf2f(j == 0 ? zq.x : zq.y);
      bfu r = f2bf(y * sz);
      if (j == 0) oq.x = r; else oq.y = r;
    }
    *(ushort2*)(yz + base + (size_t)i * 768) = oq;
  }
}

extern "C" void kernel_launch(void* const* d_in, const int* in_sizes, int n_in,
                              void* d_out, int out_size, void* d_ws, size_t ws_size,
                              hipStream_t stream){
  const float* x     = (const float*)d_in[0];
  const float* W_in  = (const float*)d_in[1];
  const float* A_log = (const float*)d_in[2];
  const float* D_par = (const float*)d_in[3];
  const float* W_x   = (const float*)d_in[4];
  const float* W_dt  = (const float*)d_in[5];
  const float* b_dt  = (const float*)d_in[6];
  const float* W_out = (const float*)d_in[7];
  float* out = (float*)d_out;
  (void)in_sizes; (void)n_in; (void)out_size; (void)ws_size;

  char* base = (char*)d_ws;
  size_t off = 0;
  auto alloc = [&](size_t bytes)->char*{
    char* p = base + off; off += (bytes + 255) & ~(size_t)255; return p;
  };
  bfu*   x_bf  = (bfu*)  alloc((size_t)16384 * 512 * 2);
  bfu*   WinT  = (bfu*)  alloc((size_t)1536 * 512 * 2);
  bfu*   WoutT = (bfu*)  alloc((size_t)512 * 768 * 2);
  float* WxT   = (float*)alloc((size_t)8 * 768 * 4);
  bfu*   xssm  = (bfu*)  alloc((size_t)16384 * 768 * 2);
  bfu*   siluz = (bfu*)  alloc((size_t)16384 * 768 * 2);
  float* u     = (float*)alloc((size_t)16384 * 8 * 4);
  float* Pws   = (float*)alloc((size_t)8 * 64 * 768 * 8 * 4);
  float* Hws   = (float*)alloc((size_t)8 * 64 * 768 * 8 * 4);
  bfu*   yz    = (bfu*)  alloc((size_t)16384 * 768 * 2);

  // 1) convert x to bf16
  cvt4_kernel<<<8192, 256, 0, stream>>>(x, x_bf, 2097152);
  // 2) transpose+convert weights (+ WxT)
  cvtT2_kernel<<<4632, 256, 0, stream>>>(W_in, W_out, W_x, WinT, WoutT, WxT);
  // 3) GEMM1: xz = x @ W_in, fused silu + split -> xssm, siluz (bf16)
  //    grid = (1536/128) x (16384/256) = 12 x 64 = 768 blocks
  gemm_big<0><<<768, 512, 0, stream>>>(x_bf, WinT, xssm, siluz, 12, 1536, 512);
  // 4) u = xssm @ W_x
  u_kernel<<<4096, 256, 0, stream>>>(xssm, WxT, u);
  // 5-7) chunked scan (delta recomputed inline from u)
  scan_phase1<<<1536, 128, 0, stream>>>(xssm, u, W_dt, b_dt, A_log, Pws, Hws);
  scan_phase2<<<192, 256, 0, stream>>>(Pws, Hws);
  scan_phase3<<<1536, 128, 0, stream>>>(xssm, u, W_dt, b_dt, A_log, D_par, siluz, Pws, yz);
  // 8) out = yz @ W_out (f32 out), grid = (512/128) x (16384/256) = 4 x 64 = 256 blocks
  gemm_big<1><<<256, 512, 0, stream>>>(yz, WoutT, out, nullptr, 4, 512, 768);
}

// Round 6
// 168.518 us; speedup vs baseline: 1.6126x; 1.0122x over previous
//
#include <hip/hip_runtime.h>

typedef unsigned short bfu;
typedef __attribute__((ext_vector_type(8))) short short8;
typedef __attribute__((ext_vector_type(4))) float f32x4;

__device__ __forceinline__ float bf2f(bfu u){
  union { unsigned int i; float f; } v; v.i = ((unsigned int)u) << 16; return v.f;
}
__device__ __forceinline__ bfu f2bf(float f){
  union { float f; unsigned int i; } v; v.f = f;
  unsigned int r = (v.i + 0x7FFFu + ((v.i >> 16) & 1u)) >> 16;
  return (bfu)r;
}
// raw HW transcendentals (v_exp_f32 / v_log_f32); denormal flush is fine here
__device__ __forceinline__ float fexp2(float x){ return __builtin_amdgcn_exp2f(x); }
__device__ __forceinline__ float flog2(float x){ return __builtin_amdgcn_logf(x); }
// fast softplus: max(x,0) + ln2*log2(1+exp2(-|x|*log2e)) ; 6 VALU + 2 trans
__device__ __forceinline__ float softplusf(float x){
  float t = fexp2(-fabsf(x) * 1.44269504088896f);
  return fmaxf(x, 0.f) + 0.69314718055995f * flog2(1.f + t);
}
__device__ __forceinline__ void gload16(const bfu* g, bfu* l){
  __builtin_amdgcn_global_load_lds((const __attribute__((address_space(1))) unsigned int*)g,
                                   (__attribute__((address_space(3))) unsigned int*)l, 16, 0, 0);
}

// ---------------- fused conversion kernel ----------------
// part 1: x (f32) -> x_bf, 2097152 float4 groups (blocks 0..8191)
// part 2: W_in->WinT (1536x512 bf16), W_out->WoutT (512x768 bf16), W_x->WxT (8x768 f32)
__global__ __launch_bounds__(256) void cvt_all_kernel(const float* __restrict__ x, bfu* __restrict__ x_bf,
                                                      const float* __restrict__ W_in, const float* __restrict__ W_out,
                                                      const float* __restrict__ W_x,
                                                      bfu* __restrict__ WinT, bfu* __restrict__ WoutT,
                                                      float* __restrict__ WxT){
  int g = blockIdx.x * 256 + threadIdx.x;
  if (g < 2097152){
    float4 v = ((const float4*)x)[g];
    ushort4 o;
    o.x = f2bf(v.x); o.y = f2bf(v.y); o.z = f2bf(v.z); o.w = f2bf(v.w);
    ((ushort4*)x_bf)[g] = o;
    return;
  }
  int h = g - 2097152;
  if (h < 786432){
    int r = h % 512, c = h / 512;
    WinT[h] = f2bf(W_in[(size_t)r * 1536 + c]);
  } else if (h < 786432 + 393216){
    int h2 = h - 786432;
    int r = h2 % 768, c = h2 / 768;
    WoutT[h2] = f2bf(W_out[(size_t)r * 512 + c]);
  } else if (h < 786432 + 393216 + 6144){
    int h2 = h - (786432 + 393216);
    int n = h2 / 768, k = h2 % 768;
    WxT[h2] = W_x[(size_t)k * 8 + n];
  }
}

// ---------------- MFMA GEMM: C = A(MxK) * Bt(NxK)^T ----------------
// 128x128 tile, BK=64, DOUBLE-buffered LDS, counted vmcnt pipeline (T3/T4),
// raw s_barrier, setprio around MFMA (T5), XCD-swizzled blocks (T1),
// XOR-swizzled LDS via pre-swizzled global source (T2).  K compile-time.
template<int EPI, int KK>
__global__ __launch_bounds__(256)
void gemm_db(const bfu* __restrict__ Amat, const bfu* __restrict__ Bt,
             void* __restrict__ out0, void* __restrict__ out1,
             int NBN, int N)
{
  constexpr int NT = KK / 64;
  __shared__ bfu As[2 * 128 * 64];
  __shared__ bfu Bs[2 * 128 * 64];
  const int tid  = threadIdx.x;
  const int lane = tid & 63;
  const int w    = tid >> 6;
  const int wr   = w >> 1, wc = w & 1;   // 2 x 2 wave grid

  // XCD-aware bijective swizzle (grid % 8 == 0)
  const int cpx = gridDim.x >> 3;
  const int id  = blockIdx.x;
  const int nid = (id & 7) * cpx + (id >> 3);
  const int bn  = nid % NBN;
  const int bm  = nid / NBN;

  // staging: issue i covers rows i*32..i*32+31; thread t -> row i*32+(t>>3), slot t&7
  // LDS dest LINEAR (tid*8 elems); global col pre-swizzled (T2, both-sides rule)
  const int srow = tid >> 3;             // 0..31
  const int scol = ((tid & 7) ^ (srow & 7)) * 8;
  const bfu* gA = Amat + ((size_t)(bm * 128 + srow)) * KK + scol;
  const bfu* gB = Bt   + ((size_t)(bn * 128 + srow)) * KK + scol;
  bfu* lA = As + tid * 8;
  bfu* lB = Bs + tid * 8;

  auto STAGE = [&](int t, int sel){
    const int k0 = t * 64;
    #pragma unroll
    for (int i = 0; i < 4; i++){
      gload16(gA + (size_t)(i * 32) * KK + k0, lA + sel * 8192 + i * 2048);
      gload16(gB + (size_t)(i * 32) * KK + k0, lB + sel * 8192 + i * 2048);
    }
  };

  f32x4 acc[4][4];
  #pragma unroll
  for (int i = 0; i < 4; i++)
    #pragma unroll
    for (int j = 0; j < 4; j++)
      #pragma unroll
      for (int r = 0; r < 4; r++) acc[i][j][r] = 0.f;

  STAGE(0, 0);
  STAGE(1, 1);

  #pragma unroll
  for (int t = 0; t < NT; ++t){
    // counted wait: oldest 8 (tile t) landed; tile t+1's 8 stay in flight (T4)
    if (t + 1 < NT) asm volatile("s_waitcnt vmcnt(8)" ::: "memory");
    else            asm volatile("s_waitcnt vmcnt(0)" ::: "memory");
    __builtin_amdgcn_s_barrier();

    const bfu* Ab = As + (t & 1) * 8192;
    const bfu* Bb = Bs + (t & 1) * 8192;
    #pragma unroll
    for (int kk = 0; kk < 2; kk++){
      short8 a[4], b[4];
      const int sA = ((kk * 4 + (lane >> 4)) ^ (lane & 7)) * 8;
      #pragma unroll
      for (int m = 0; m < 4; m++){
        int r = wr * 64 + m * 16 + (lane & 15);
        a[m] = *(const short8*)&Ab[r * 64 + sA];
      }
      #pragma unroll
      for (int n = 0; n < 4; n++){
        int r = wc * 64 + n * 16 + (lane & 15);
        b[n] = *(const short8*)&Bb[r * 64 + sA];
      }
      __builtin_amdgcn_s_setprio(1);
      #pragma unroll
      for (int m = 0; m < 4; m++)
        #pragma unroll
        for (int n = 0; n < 4; n++)
          acc[m][n] = __builtin_amdgcn_mfma_f32_16x16x32_bf16(a[m], b[n], acc[m][n], 0, 0, 0);
      __builtin_amdgcn_s_setprio(0);
    }
    __builtin_amdgcn_s_barrier();   // all waves done reading buf (t&1)
    if (t + 2 < NT) STAGE(t + 2, t & 1);
  }

  #pragma unroll
  for (int m = 0; m < 4; m++){
    #pragma unroll
    for (int n = 0; n < 4; n++){
      const int row0 = bm * 128 + wr * 64 + m * 16 + (lane >> 4) * 4;
      const int col  = bn * 128 + wc * 64 + n * 16 + (lane & 15);
      #pragma unroll
      for (int r = 0; r < 4; r++){
        float v = acc[m][n][r];
        int row = row0 + r;
        if (EPI == 0){
          float s = v / (1.f + __expf(-v));   // silu
          if (col < 768) ((bfu*)out0)[(size_t)row * 768 + col]         = f2bf(s);
          else           ((bfu*)out1)[(size_t)row * 768 + (col - 768)] = f2bf(s);
        } else {
          ((float*)out0)[(size_t)row * N + col] = v;
        }
      }
    }
  }
}

// ---------------- u = xssm @ W_x  (uses WxT [8][768], coalesced) ----------------
__global__ __launch_bounds__(256) void u_kernel(const bfu* __restrict__ xssm, const float* __restrict__ WxT,
                                                float* __restrict__ u){
  int wid = threadIdx.x >> 6, lane = threadIdx.x & 63;
  int row = blockIdx.x * 4 + wid;
  const bfu* xr = xssm + (size_t)row * 768;
  float acc[8];
  #pragma unroll
  for (int n = 0; n < 8; n++) acc[n] = 0.f;
  #pragma unroll
  for (int i = 0; i < 3; i++){
    int kb = i * 256 + lane * 4;
    ushort4 xq = *(const ushort4*)(xr + kb);
    float x0 = bf2f(xq.x), x1 = bf2f(xq.y), x2 = bf2f(xq.z), x3 = bf2f(xq.w);
    #pragma unroll
    for (int n = 0; n < 8; n++){
      float4 wv = *(const float4*)(WxT + (size_t)n * 768 + kb);
      acc[n] += x0 * wv.x + x1 * wv.y + x2 * wv.z + x3 * wv.w;
    }
  }
  #pragma unroll
  for (int n = 0; n < 8; n++){
    #pragma unroll
    for (int off = 32; off >= 1; off >>= 1) acc[n] += __shfl_xor(acc[n], off, 64);
  }
  if (lane == 0){
    float4 o0 = { acc[0], acc[1], acc[2], acc[3] };
    float4 o1 = { acc[4], acc[5], acc[6], acc[7] };
    *(float4*)(u + (size_t)row * 8)     = o0;
    *(float4*)(u + (size_t)row * 8 + 4) = o1;
  }
}

// ---------------- scan phase 1: per-chunk local scan, delta inline ----------------
__global__ __launch_bounds__(128) void scan_phase1(const bfu* __restrict__ xssm, const float* __restrict__ u,
    const float* __restrict__ Wdt, const float* __restrict__ bdt, const float* __restrict__ A_log,
    float* __restrict__ Pws, float* __restrict__ Hws){
  int tid = threadIdx.x;
  int bid = blockIdx.x;
  int b = bid / 192; int rem = bid % 192;
  int c = rem / 3;   int dblk = rem % 3;
  int d0 = dblk * 256 + tid * 2;
  float Al2[2][8], H[2][8], Wr[2][8], bd[2], S[2];
  #pragma unroll
  for (int j = 0; j < 2; j++){
    bd[j] = bdt[d0 + j];
    S[j] = 0.f;
    #pragma unroll
    for (int n = 0; n < 8; n++){
      Al2[j][n] = -__expf(A_log[(size_t)(d0 + j) * 8 + n]) * 1.4426950408889634f;
      Wr[j][n]  = Wdt[(size_t)n * 768 + d0 + j];
      H[j][n] = 0.f;
    }
  }
  int r0 = b * 2048 + c * 32;
  size_t base = (size_t)r0 * 768 + d0;
  #pragma unroll 8
  for (int i = 0; i < 32; i++){
    float4 u0 = *(const float4*)(u + (size_t)(r0 + i) * 8);
    float4 u1 = *(const float4*)(u + (size_t)(r0 + i) * 8 + 4);
    ushort2 xq = *(const ushort2*)(xssm + base + (size_t)i * 768);
    #pragma unroll
    for (int j = 0; j < 2; j++){
      float xt = bf2f(j == 0 ? xq.x : xq.y);
      float dv = bd[j] + u0.x * Wr[j][0] + u0.y * Wr[j][1] + u0.z * Wr[j][2] + u0.w * Wr[j][3]
                       + u1.x * Wr[j][4] + u1.y * Wr[j][5] + u1.z * Wr[j][6] + u1.w * Wr[j][7];
      float dt = softplusf(dv);
      float dx = dt * xt;
      S[j] += dt;
      #pragma unroll
      for (int n = 0; n < 8; n++){
        float e = fexp2(dt * Al2[j][n]);
        H[j][n] = e * H[j][n] + dx;
      }
    }
  }
  size_t o = (((size_t)b * 64 + c) * 768 + d0) * 8;
  #pragma unroll
  for (int j = 0; j < 2; j++){
    float4 p0, p1;
    p0.x = fexp2(S[j] * Al2[j][0]); p0.y = fexp2(S[j] * Al2[j][1]);
    p0.z = fexp2(S[j] * Al2[j][2]); p0.w = fexp2(S[j] * Al2[j][3]);
    p1.x = fexp2(S[j] * Al2[j][4]); p1.y = fexp2(S[j] * Al2[j][5]);
    p1.z = fexp2(S[j] * Al2[j][6]); p1.w = fexp2(S[j] * Al2[j][7]);
    float4 h0 = { H[j][0], H[j][1], H[j][2], H[j][3] };
    float4 h1 = { H[j][4], H[j][5], H[j][6], H[j][7] };
    *(float4*)(Pws + o + j * 8)     = p0;
    *(float4*)(Pws + o + j * 8 + 4) = p1;
    *(float4*)(Hws + o + j * 8)     = h0;
    *(float4*)(Hws + o + j * 8 + 4) = h1;
  }
}

// ---------------- scan phase 2: combine chunks; Hin written IN-PLACE into Pws ----------------
__global__ __launch_bounds__(256) void scan_phase2(float* __restrict__ Pws, const float* __restrict__ Hws){
  int g = blockIdx.x * 256 + threadIdx.x;   // 49152 = 8*768*8
  int within = g % 6144;                    // d*8+n
  int b = g / 6144;
  size_t base = (size_t)b * 64 * 6144 + within;
  float hin = 0.f;
  #pragma unroll 8
  for (int c = 0; c < 64; c++){
    size_t idx = base + (size_t)c * 6144;
    float p = Pws[idx], hh = Hws[idx];
    Pws[idx] = hin;                         // h_in for chunk c
    hin = p * hin + hh;
  }
}

// ---------------- scan phase 3: re-run chunk with h_in, delta inline, fuse gate ----------------
__global__ __launch_bounds__(128) void scan_phase3(const bfu* __restrict__ xssm, const float* __restrict__ u,
    const float* __restrict__ Wdt, const float* __restrict__ bdt, const float* __restrict__ A_log,
    const float* __restrict__ Dp, const bfu* __restrict__ siluz, const float* __restrict__ Hin,
    bfu* __restrict__ yz){
  int tid = threadIdx.x;
  int bid = blockIdx.x;
  int b = bid / 192; int rem = bid % 192;
  int c = rem / 3;   int dblk = rem % 3;
  int d0 = dblk * 256 + tid * 2;
  float Al2[2][8], H[2][8], Wr[2][8], bd[2], Dd[2];
  size_t o = (((size_t)b * 64 + c) * 768 + d0) * 8;
  #pragma unroll
  for (int j = 0; j < 2; j++){
    bd[j] = bdt[d0 + j];
    Dd[j] = Dp[d0 + j];
    float4 h0 = *(const float4*)(Hin + o + j * 8);
    float4 h1 = *(const float4*)(Hin + o + j * 8 + 4);
    H[j][0] = h0.x; H[j][1] = h0.y; H[j][2] = h0.z; H[j][3] = h0.w;
    H[j][4] = h1.x; H[j][5] = h1.y; H[j][6] = h1.z; H[j][7] = h1.w;
    #pragma unroll
    for (int n = 0; n < 8; n++){
      Al2[j][n] = -__expf(A_log[(size_t)(d0 + j) * 8 + n]) * 1.4426950408889634f;
      Wr[j][n]  = Wdt[(size_t)n * 768 + d0 + j];
    }
  }
  int r0 = b * 2048 + c * 32;
  size_t base = (size_t)r0 * 768 + d0;
  #pragma unroll 8
  for (int i = 0; i < 32; i++){
    float4 u0 = *(const float4*)(u + (size_t)(r0 + i) * 8);
    float4 u1 = *(const float4*)(u + (size_t)(r0 + i) * 8 + 4);
    ushort2 xq = *(const ushort2*)(xssm + base + (size_t)i * 768);
    ushort2 zq = *(const ushort2*)(siluz + base + (size_t)i * 768);
    ushort2 oq;
    #pragma unroll
    for (int j = 0; j < 2; j++){
      float xt = bf2f(j == 0 ? xq.x : xq.y);
      float dv = bd[j] + u0.x * Wr[j][0] + u0.y * Wr[j][1] + u0.z * Wr[j][2] + u0.w * Wr[j][3]
                       + u1.x * Wr[j][4] + u1.y * Wr[j][5] + u1.z * Wr[j][6] + u1.w * Wr[j][7];
      float dt = softplusf(dv);
      float dx = dt * xt;
      float y = Dd[j] * xt;
      #pragma unroll
      for (int n = 0; n < 8; n++){
        float e = fexp2(dt * Al2[j][n]);
        H[j][n] = e * H[j][n] + dx;
        y += H[j][n];
      }
      float sz = bf2f(j == 0 ? zq.x : zq.y);
      bfu r = f2bf(y * sz);
      if (j == 0) oq.x = r; else oq.y = r;
    }
    *(ushort2*)(yz + base + (size_t)i * 768) = oq;
  }
}

extern "C" void kernel_launch(void* const* d_in, const int* in_sizes, int n_in,
                              void* d_out, int out_size, void* d_ws, size_t ws_size,
                              hipStream_t stream){
  const float* x     = (const float*)d_in[0];
  const float* W_in  = (const float*)d_in[1];
  const float* A_log = (const float*)d_in[2];
  const float* D_par = (const float*)d_in[3];
  const float* W_x   = (const float*)d_in[4];
  const float* W_dt  = (const float*)d_in[5];
  const float* b_dt  = (const float*)d_in[6];
  const float* W_out = (const float*)d_in[7];
  float* out = (float*)d_out;
  (void)in_sizes; (void)n_in; (void)out_size; (void)ws_size;

  char* base = (char*)d_ws;
  size_t off = 0;
  auto alloc = [&](size_t bytes)->char*{
    char* p = base + off; off += (bytes + 255) & ~(size_t)255; return p;
  };
  bfu*   x_bf  = (bfu*)  alloc((size_t)16384 * 512 * 2);
  bfu*   WinT  = (bfu*)  alloc((size_t)1536 * 512 * 2);
  bfu*   WoutT = (bfu*)  alloc((size_t)512 * 768 * 2);
  float* WxT   = (float*)alloc((size_t)8 * 768 * 4);
  bfu*   xssm  = (bfu*)  alloc((size_t)16384 * 768 * 2);
  bfu*   siluz = (bfu*)  alloc((size_t)16384 * 768 * 2);
  float* u     = (float*)alloc((size_t)16384 * 8 * 4);
  float* Pws   = (float*)alloc((size_t)8 * 64 * 768 * 8 * 4);
  float* Hws   = (float*)alloc((size_t)8 * 64 * 768 * 8 * 4);
  bfu*   yz    = (bfu*)  alloc((size_t)16384 * 768 * 2);

  // 1) fused conversions: x->bf16, W_in/W_out transpose->bf16, W_x->WxT
  cvt_all_kernel<<<12824, 256, 0, stream>>>(x, x_bf, W_in, W_out, W_x, WinT, WoutT, WxT);
  // 2) GEMM1: xz = x @ W_in, fused silu + split -> xssm, siluz (bf16)
  //    grid = (1536/128)*(16384/128) = 12*128 = 1536 blocks
  gemm_db<0, 512><<<1536, 256, 0, stream>>>(x_bf, WinT, xssm, siluz, 12, 1536);
  // 3) u = xssm @ W_x
  u_kernel<<<4096, 256, 0, stream>>>(xssm, WxT, u);
  // 4-6) chunked scan (delta recomputed inline from u)
  scan_phase1<<<1536, 128, 0, stream>>>(xssm, u, W_dt, b_dt, A_log, Pws, Hws);
  scan_phase2<<<192, 256, 0, stream>>>(Pws, Hws);
  scan_phase3<<<1536, 128, 0, stream>>>(xssm, u, W_dt, b_dt, A_log, D_par, siluz, Pws, yz);
  // 7) out = yz @ W_out (f32 out), grid = (512/128)*(16384/128) = 4*128 = 512 blocks
  gemm_db<1, 768><<<512, 256, 0, stream>>>(yz, WoutT, out, nullptr, 4, 512);
}

// Round 7
// 166.110 us; speedup vs baseline: 1.6360x; 1.0145x over previous
//
#include <hip/hip_runtime.h>

typedef unsigned short bfu;
typedef __attribute__((ext_vector_type(8))) short short8;
typedef __attribute__((ext_vector_type(4))) float f32x4;

__device__ __forceinline__ float bf2f(bfu u){
  union { unsigned int i; float f; } v; v.i = ((unsigned int)u) << 16; return v.f;
}
__device__ __forceinline__ bfu f2bf(float f){
  union { float f; unsigned int i; } v; v.f = f;
  unsigned int r = (v.i + 0x7FFFu + ((v.i >> 16) & 1u)) >> 16;
  return (bfu)r;
}
__device__ __forceinline__ float fexp2(float x){ return __builtin_amdgcn_exp2f(x); }
__device__ __forceinline__ float flog2(float x){ return __builtin_amdgcn_logf(x); }
__device__ __forceinline__ float softplusf(float x){
  float t = fexp2(-fabsf(x) * 1.44269504088896f);
  return fmaxf(x, 0.f) + 0.69314718055995f * flog2(1.f + t);
}
__device__ __forceinline__ void gload16(const bfu* g, bfu* l){
  __builtin_amdgcn_global_load_lds((const __attribute__((address_space(1))) unsigned int*)g,
                                   (__attribute__((address_space(3))) unsigned int*)l, 16, 0, 0);
}

// ---------------- fused conversion kernel ----------------
__global__ __launch_bounds__(256) void cvt_all_kernel(const float* __restrict__ x, bfu* __restrict__ x_bf,
                                                      const float* __restrict__ W_in, const float* __restrict__ W_out,
                                                      const float* __restrict__ W_x,
                                                      bfu* __restrict__ WinT, bfu* __restrict__ WoutT,
                                                      float* __restrict__ WxT){
  int g = blockIdx.x * 256 + threadIdx.x;
  if (g < 2097152){
    float4 v = ((const float4*)x)[g];
    ushort4 o;
    o.x = f2bf(v.x); o.y = f2bf(v.y); o.z = f2bf(v.z); o.w = f2bf(v.w);
    ((ushort4*)x_bf)[g] = o;
    return;
  }
  int h = g - 2097152;
  if (h < 786432){
    int r = h % 512, c = h / 512;
    WinT[h] = f2bf(W_in[(size_t)r * 1536 + c]);
  } else if (h < 786432 + 393216){
    int h2 = h - 786432;
    int r = h2 % 768, c = h2 / 768;
    WoutT[h2] = f2bf(W_out[(size_t)r * 512 + c]);
  } else if (h < 786432 + 393216 + 6144){
    int h2 = h - (786432 + 393216);
    int n = h2 / 768, k = h2 % 768;
    WxT[h2] = W_x[(size_t)k * 8 + n];
  }
}

// ---------------- MFMA GEMM: C = A(MxK) * Bt(NxK)^T ----------------
// BM=128, BN=256, BK=64, 512 thr (8 waves: 2M x 4N, 64x64/wave).
// TRIPLE-buffered LDS (3 x 48KB), one s_barrier + counted vmcnt(6) per K-tile,
// stage tile t+2 during tile t (8-phase prefetch lead), setprio on MFMA (T5),
// XCD-swizzled blocks (T1), XOR-swizzled LDS via pre-swizzled source (T2).
template<int EPI, int KK>
__global__ __launch_bounds__(512)
void gemm_3s(const bfu* __restrict__ Amat, const bfu* __restrict__ Bt,
             void* __restrict__ out0, void* __restrict__ out1,
             int NBN, int N)
{
  constexpr int NT = KK / 64;
  // per buf: A 128x64 (8192 elems) + B 256x64 (16384 elems) = 24576 elems (48KB)
  __shared__ bfu LDS[3 * 24576];
  const int tid  = threadIdx.x;
  const int lane = tid & 63;
  const int w    = tid >> 6;
  const int wr   = w >> 2, wc = w & 3;   // 2 x 4 wave grid

  // XCD-aware bijective swizzle (grid % 8 == 0)
  const int cpx = gridDim.x >> 3;
  const int id  = blockIdx.x;
  const int nid = (id & 7) * cpx + (id >> 3);
  const int bn  = nid % NBN;
  const int bm  = nid / NBN;

  // staging: set covers 64 rows; thread t -> row (t>>3), 16B slot (t&7)
  const int srow = tid >> 3;             // 0..63
  const int scol = ((tid & 7) ^ (srow & 7)) * 8;   // pre-swizzled global col (T2)
  const bfu* gA = Amat + ((size_t)(bm * 128 + srow)) * KK + scol;
  const bfu* gB = Bt   + ((size_t)(bn * 256 + srow)) * KK + scol;

  // stage tile t into buffer buf: A 2 sets, B 4 sets (6 gloads/thread)
  auto STAGE = [&](int t, int buf){
    const int k0 = t * 64;
    bfu* dst = LDS + buf * 24576 + tid * 8;
    #pragma unroll
    for (int i = 0; i < 2; i++)
      gload16(gA + (size_t)(i * 64) * KK + k0, dst + i * 4096);
    #pragma unroll
    for (int j = 0; j < 4; j++)
      gload16(gB + (size_t)(j * 64) * KK + k0, dst + 8192 + j * 4096);
  };

  f32x4 acc[4][4];
  #pragma unroll
  for (int i = 0; i < 4; i++)
    #pragma unroll
    for (int j = 0; j < 4; j++)
      #pragma unroll
      for (int r = 0; r < 4; r++) acc[i][j][r] = 0.f;

  STAGE(0, 0);
  STAGE(1, 1);

  #pragma unroll
  for (int t = 0; t < NT; ++t){
    // boundary: tile t's 6 loads are the oldest; tile t+1's 6 may stay in flight
    if (t + 1 < NT) asm volatile("s_waitcnt vmcnt(6)" ::: "memory");
    else            asm volatile("s_waitcnt vmcnt(0)" ::: "memory");
    __builtin_amdgcn_s_barrier();

    if (t + 2 < NT) STAGE(t + 2, (t + 2) % 3);   // into buffer freed by tile t-1

    const bfu* Ab = LDS + (t % 3) * 24576;
    const bfu* Bb = Ab + 8192;
    short8 a[2][2], b[4][2];

    // ds_read helpers (swizzled slot), all indices compile-time
    #define LDA(mh)                                                             \
      _Pragma("unroll") for (int mi = 0; mi < 2; mi++)                          \
      _Pragma("unroll") for (int kk = 0; kk < 2; kk++){                         \
        int r_ = wr * 64 + ((mh) * 2 + mi) * 16 + (lane & 15);                  \
        int s_ = (kk * 4 + (lane >> 4)) ^ (r_ & 7);                             \
        a[mi][kk] = *(const short8*)&Ab[r_ * 64 + s_ * 8];                      \
      }
    #define LDB(nh)                                                             \
      _Pragma("unroll") for (int ni = 0; ni < 2; ni++)                          \
      _Pragma("unroll") for (int kk = 0; kk < 2; kk++){                         \
        int r_ = wc * 64 + ((nh) * 2 + ni) * 16 + (lane & 15);                  \
        int s_ = (kk * 4 + (lane >> 4)) ^ (r_ & 7);                             \
        b[(nh) * 2 + ni][kk] = *(const short8*)&Bb[r_ * 64 + s_ * 8];           \
      }
    #define MFMA8(mh, nh)                                                       \
      __builtin_amdgcn_s_setprio(1);                                            \
      _Pragma("unroll") for (int mi = 0; mi < 2; mi++)                          \
      _Pragma("unroll") for (int ni = 0; ni < 2; ni++)                          \
      _Pragma("unroll") for (int kk = 0; kk < 2; kk++)                          \
        acc[(mh)*2+mi][(nh)*2+ni] = __builtin_amdgcn_mfma_f32_16x16x32_bf16(    \
            a[mi][kk], b[(nh)*2+ni][kk], acc[(mh)*2+mi][(nh)*2+ni], 0, 0, 0);   \
      __builtin_amdgcn_s_setprio(0);

    LDA(0); LDB(0);
    MFMA8(0, 0);        // q0
    LDB(1);
    MFMA8(0, 1);        // q1
    LDA(1);
    MFMA8(1, 0);        // q2 (b[0..1] still live)
    MFMA8(1, 1);        // q3
    #undef LDA
    #undef LDB
    #undef MFMA8
  }

  #pragma unroll
  for (int m = 0; m < 4; m++){
    #pragma unroll
    for (int n = 0; n < 4; n++){
      const int row0 = bm * 128 + wr * 64 + m * 16 + (lane >> 4) * 4;
      const int col  = bn * 256 + wc * 64 + n * 16 + (lane & 15);
      #pragma unroll
      for (int r = 0; r < 4; r++){
        float v = acc[m][n][r];
        int row = row0 + r;
        if (EPI == 0){
          float s = v / (1.f + __expf(-v));   // silu
          if (col < 768) ((bfu*)out0)[(size_t)row * 768 + col]         = f2bf(s);
          else           ((bfu*)out1)[(size_t)row * 768 + (col - 768)] = f2bf(s);
        } else {
          ((float*)out0)[(size_t)row * N + col] = v;
        }
      }
    }
  }
}

// ---------------- u = xssm @ W_x  (uses WxT [8][768], coalesced) ----------------
__global__ __launch_bounds__(256) void u_kernel(const bfu* __restrict__ xssm, const float* __restrict__ WxT,
                                                float* __restrict__ u){
  int wid = threadIdx.x >> 6, lane = threadIdx.x & 63;
  int row = blockIdx.x * 4 + wid;
  const bfu* xr = xssm + (size_t)row * 768;
  float acc[8];
  #pragma unroll
  for (int n = 0; n < 8; n++) acc[n] = 0.f;
  #pragma unroll
  for (int i = 0; i < 3; i++){
    int kb = i * 256 + lane * 4;
    ushort4 xq = *(const ushort4*)(xr + kb);
    float x0 = bf2f(xq.x), x1 = bf2f(xq.y), x2 = bf2f(xq.z), x3 = bf2f(xq.w);
    #pragma unroll
    for (int n = 0; n < 8; n++){
      float4 wv = *(const float4*)(WxT + (size_t)n * 768 + kb);
      acc[n] += x0 * wv.x + x1 * wv.y + x2 * wv.z + x3 * wv.w;
    }
  }
  #pragma unroll
  for (int n = 0; n < 8; n++){
    #pragma unroll
    for (int off = 32; off >= 1; off >>= 1) acc[n] += __shfl_xor(acc[n], off, 64);
  }
  if (lane == 0){
    float4 o0 = { acc[0], acc[1], acc[2], acc[3] };
    float4 o1 = { acc[4], acc[5], acc[6], acc[7] };
    *(float4*)(u + (size_t)row * 8)     = o0;
    *(float4*)(u + (size_t)row * 8 + 4) = o1;
  }
}

// ---------------- scan phase 1: per-chunk local scan, delta inline ----------------
__global__ __launch_bounds__(128) void scan_phase1(const bfu* __restrict__ xssm, const float* __restrict__ u,
    const float* __restrict__ Wdt, const float* __restrict__ bdt, const float* __restrict__ A_log,
    float* __restrict__ Pws, float* __restrict__ Hws){
  int tid = threadIdx.x;
  int bid = blockIdx.x;
  int b = bid / 192; int rem = bid % 192;
  int c = rem / 3;   int dblk = rem % 3;
  int d0 = dblk * 256 + tid * 2;
  float Al2[2][8], H[2][8], Wr[2][8], bd[2], S[2];
  #pragma unroll
  for (int j = 0; j < 2; j++){
    bd[j] = bdt[d0 + j];
    S[j] = 0.f;
    #pragma unroll
    for (int n = 0; n < 8; n++){
      Al2[j][n] = -__expf(A_log[(size_t)(d0 + j) * 8 + n]) * 1.4426950408889634f;
      Wr[j][n]  = Wdt[(size_t)n * 768 + d0 + j];
      H[j][n] = 0.f;
    }
  }
  int r0 = b * 2048 + c * 32;
  size_t base = (size_t)r0 * 768 + d0;
  #pragma unroll 8
  for (int i = 0; i < 32; i++){
    float4 u0 = *(const float4*)(u + (size_t)(r0 + i) * 8);
    float4 u1 = *(const float4*)(u + (size_t)(r0 + i) * 8 + 4);
    ushort2 xq = *(const ushort2*)(xssm + base + (size_t)i * 768);
    #pragma unroll
    for (int j = 0; j < 2; j++){
      float xt = bf2f(j == 0 ? xq.x : xq.y);
      float dv = bd[j] + u0.x * Wr[j][0] + u0.y * Wr[j][1] + u0.z * Wr[j][2] + u0.w * Wr[j][3]
                       + u1.x * Wr[j][4] + u1.y * Wr[j][5] + u1.z * Wr[j][6] + u1.w * Wr[j][7];
      float dt = softplusf(dv);
      float dx = dt * xt;
      S[j] += dt;
      #pragma unroll
      for (int n = 0; n < 8; n++){
        float e = fexp2(dt * Al2[j][n]);
        H[j][n] = e * H[j][n] + dx;
      }
    }
  }
  size_t o = (((size_t)b * 64 + c) * 768 + d0) * 8;
  #pragma unroll
  for (int j = 0; j < 2; j++){
    float4 p0, p1;
    p0.x = fexp2(S[j] * Al2[j][0]); p0.y = fexp2(S[j] * Al2[j][1]);
    p0.z = fexp2(S[j] * Al2[j][2]); p0.w = fexp2(S[j] * Al2[j][3]);
    p1.x = fexp2(S[j] * Al2[j][4]); p1.y = fexp2(S[j] * Al2[j][5]);
    p1.z = fexp2(S[j] * Al2[j][6]); p1.w = fexp2(S[j] * Al2[j][7]);
    float4 h0 = { H[j][0], H[j][1], H[j][2], H[j][3] };
    float4 h1 = { H[j][4], H[j][5], H[j][6], H[j][7] };
    *(float4*)(Pws + o + j * 8)     = p0;
    *(float4*)(Pws + o + j * 8 + 4) = p1;
    *(float4*)(Hws + o + j * 8)     = h0;
    *(float4*)(Hws + o + j * 8 + 4) = h1;
  }
}

// ---------------- scan phase 2: combine chunks; Hin written IN-PLACE into Pws ----------------
__global__ __launch_bounds__(256) void scan_phase2(float* __restrict__ Pws, const float* __restrict__ Hws){
  int g = blockIdx.x * 256 + threadIdx.x;   // 49152 = 8*768*8
  int within = g % 6144;                    // d*8+n
  int b = g / 6144;
  size_t base = (size_t)b * 64 * 6144 + within;
  float hin = 0.f;
  #pragma unroll 8
  for (int c = 0; c < 64; c++){
    size_t idx = base + (size_t)c * 6144;
    float p = Pws[idx], hh = Hws[idx];
    Pws[idx] = hin;                         // h_in for chunk c
    hin = p * hin + hh;
  }
}

// ---------------- scan phase 3: re-run chunk with h_in, delta inline, fuse gate ----------------
__global__ __launch_bounds__(128) void scan_phase3(const bfu* __restrict__ xssm, const float* __restrict__ u,
    const float* __restrict__ Wdt, const float* __restrict__ bdt, const float* __restrict__ A_log,
    const float* __restrict__ Dp, const bfu* __restrict__ siluz, const float* __restrict__ Hin,
    bfu* __restrict__ yz){
  int tid = threadIdx.x;
  int bid = blockIdx.x;
  int b = bid / 192; int rem = bid % 192;
  int c = rem / 3;   int dblk = rem % 3;
  int d0 = dblk * 256 + tid * 2;
  float Al2[2][8], H[2][8], Wr[2][8], bd[2], Dd[2];
  size_t o = (((size_t)b * 64 + c) * 768 + d0) * 8;
  #pragma unroll
  for (int j = 0; j < 2; j++){
    bd[j] = bdt[d0 + j];
    Dd[j] = Dp[d0 + j];
    float4 h0 = *(const float4*)(Hin + o + j * 8);
    float4 h1 = *(const float4*)(Hin + o + j * 8 + 4);
    H[j][0] = h0.x; H[j][1] = h0.y; H[j][2] = h0.z; H[j][3] = h0.w;
    H[j][4] = h1.x; H[j][5] = h1.y; H[j][6] = h1.z; H[j][7] = h1.w;
    #pragma unroll
    for (int n = 0; n < 8; n++){
      Al2[j][n] = -__expf(A_log[(size_t)(d0 + j) * 8 + n]) * 1.4426950408889634f;
      Wr[j][n]  = Wdt[(size_t)n * 768 + d0 + j];
    }
  }
  int r0 = b * 2048 + c * 32;
  size_t base = (size_t)r0 * 768 + d0;
  #pragma unroll 8
  for (int i = 0; i < 32; i++){
    float4 u0 = *(const float4*)(u + (size_t)(r0 + i) * 8);
    float4 u1 = *(const float4*)(u + (size_t)(r0 + i) * 8 + 4);
    ushort2 xq = *(const ushort2*)(xssm + base + (size_t)i * 768);
    ushort2 zq = *(const ushort2*)(siluz + base + (size_t)i * 768);
    ushort2 oq;
    #pragma unroll
    for (int j = 0; j < 2; j++){
      float xt = bf2f(j == 0 ? xq.x : xq.y);
      float dv = bd[j] + u0.x * Wr[j][0] + u0.y * Wr[j][1] + u0.z * Wr[j][2] + u0.w * Wr[j][3]
                       + u1.x * Wr[j][4] + u1.y * Wr[j][5] + u1.z * Wr[j][6] + u1.w * Wr[j][7];
      float dt = softplusf(dv);
      float dx = dt * xt;
      float y = Dd[j] * xt;
      #pragma unroll
      for (int n = 0; n < 8; n++){
        float e = fexp2(dt * Al2[j][n]);
        H[j][n] = e * H[j][n] + dx;
        y += H[j][n];
      }
      float sz = bf2f(j == 0 ? zq.x : zq.y);
      bfu r = f2bf(y * sz);
      if (j == 0) oq.x = r; else oq.y = r;
    }
    *(ushort2*)(yz + base + (size_t)i * 768) = oq;
  }
}

extern "C" void kernel_launch(void* const* d_in, const int* in_sizes, int n_in,
                              void* d_out, int out_size, void* d_ws, size_t ws_size,
                              hipStream_t stream){
  const float* x     = (const float*)d_in[0];
  const float* W_in  = (const float*)d_in[1];
  const float* A_log = (const float*)d_in[2];
  const float* D_par = (const float*)d_in[3];
  const float* W_x   = (const float*)d_in[4];
  const float* W_dt  = (const float*)d_in[5];
  const float* b_dt  = (const float*)d_in[6];
  const float* W_out = (const float*)d_in[7];
  float* out = (float*)d_out;
  (void)in_sizes; (void)n_in; (void)out_size; (void)ws_size;

  char* base = (char*)d_ws;
  size_t off = 0;
  auto alloc = [&](size_t bytes)->char*{
    char* p = base + off; off += (bytes + 255) & ~(size_t)255; return p;
  };
  bfu*   x_bf  = (bfu*)  alloc((size_t)16384 * 512 * 2);
  bfu*   WinT  = (bfu*)  alloc((size_t)1536 * 512 * 2);
  bfu*   WoutT = (bfu*)  alloc((size_t)512 * 768 * 2);
  float* WxT   = (float*)alloc((size_t)8 * 768 * 4);
  bfu*   xssm  = (bfu*)  alloc((size_t)16384 * 768 * 2);
  bfu*   siluz = (bfu*)  alloc((size_t)16384 * 768 * 2);
  float* u     = (float*)alloc((size_t)16384 * 8 * 4);
  float* Pws   = (float*)alloc((size_t)8 * 64 * 768 * 8 * 4);
  float* Hws   = (float*)alloc((size_t)8 * 64 * 768 * 8 * 4);
  bfu*   yz    = (bfu*)  alloc((size_t)16384 * 768 * 2);

  // 1) fused conversions
  cvt_all_kernel<<<12824, 256, 0, stream>>>(x, x_bf, W_in, W_out, W_x, WinT, WoutT, WxT);
  // 2) GEMM1: grid = (16384/128)*(1536/256) = 128*6 = 768 blocks (3/CU exactly)
  gemm_3s<0, 512><<<768, 512, 0, stream>>>(x_bf, WinT, xssm, siluz, 6, 1536);
  // 3) u = xssm @ W_x
  u_kernel<<<4096, 256, 0, stream>>>(xssm, WxT, u);
  // 4-6) chunked scan
  scan_phase1<<<1536, 128, 0, stream>>>(xssm, u, W_dt, b_dt, A_log, Pws, Hws);
  scan_phase2<<<192, 256, 0, stream>>>(Pws, Hws);
  scan_phase3<<<1536, 128, 0, stream>>>(xssm, u, W_dt, b_dt, A_log, D_par, siluz, Pws, yz);
  // 7) GEMM2: grid = (16384/128)*(512/256) = 128*2 = 256 blocks (1/CU exactly)
  gemm_3s<1, 768><<<256, 512, 0, stream>>>(yz, WoutT, out, nullptr, 2, 512);
}